// Round 10
// baseline (440.504 us; speedup 1.0000x reference)
//
#include <hip/hip_runtime.h>

#define QLEN 512
#define KLEN 1024
#define BATCH 8
#define HEADS 16
#define HDIM 64
#define EMBED 1024

typedef __attribute__((ext_vector_type(4))) float f32x4;
typedef __attribute__((ext_vector_type(8))) short short8;
typedef unsigned short ushort_t;
typedef unsigned char uchar_t;
typedef unsigned int uint_t;

#define MFMA16(a, b, c) __builtin_amdgcn_mfma_f32_16x16x32_bf16((a), (b), (c), 0, 0, 0)

__device__ __forceinline__ float b2f(ushort_t u) {
    union { uint_t i; float f; } c; c.i = ((uint_t)u) << 16; return c.f;
}
__device__ __forceinline__ ushort_t f2b(float x) {
    union { float f; uint_t i; } c; c.f = x;
    uint_t u = c.i;
    uint_t r = (u + 0x7FFFu + ((u >> 16) & 1u)) >> 16;
    return (ushort_t)r;
}
__device__ __forceinline__ uint_t pk2(float lo, float hi) {
    return (uint_t)f2b(lo) | ((uint_t)f2b(hi) << 16);
}
// load a "float" that may be stored as f32 or bf16
__device__ __forceinline__ float ldf(const void* p, int idx, int f32m) {
    if (f32m) return ((const float*)p)[idx];
    return b2f(((const ushort_t*)p)[idx]);
}

typedef const __attribute__((address_space(1))) void async_src_t;
typedef __attribute__((address_space(3))) void async_dst_t;

// ---------------- dtype detector ----------------
// flags[0]: 1 if float tensors are f32, 0 if bf16
// flags[1]: mask mode: 0=int32, 1=uint8, 2=bf16, 3=f32
__global__ __launch_bounds__(256) void detect_kernel(const void* mask, const void* pad, int* flags) {
    __shared__ int cnt[4];
    int tid = threadIdx.x;
    if (tid < 4) cnt[tid] = 0;
    __syncthreads();
    const uchar_t* mb = (const uchar_t*)mask;
    const uchar_t* pb = (const uchar_t*)pad;
    int lnz1 = 0, l3f1 = 0, l3f3 = 0, lpnz = 0;
    for (int off = tid; off < 4096; off += 256) {
        uchar_t v = mb[off];
        int m4 = off & 3;
        if (m4 != 0 && v != 0) lnz1++;
        if (m4 == 1 && v == 0x3F) l3f1++;
        if (m4 == 3 && v == 0x3F) l3f3++;
        uchar_t p = pb[off];
        if (m4 == 0 && p != 0) lpnz++;
    }
    atomicAdd(&cnt[0], lnz1); atomicAdd(&cnt[1], l3f1);
    atomicAdd(&cnt[2], l3f3); atomicAdd(&cnt[3], lpnz);
    __syncthreads();
    if (tid == 0) {
        flags[0] = (cnt[3] == 0) ? 1 : 0;
        int mm;
        if (cnt[0] == 0) mm = 0;
        else if (cnt[1] > 16) mm = 2;
        else if (cnt[2] > 16) mm = 3;
        else mm = 1;
        flags[1] = mm;
    }
}

// ---------------- bulk convert to bf16 (pk2-based, no inline asm) ----------------
__global__ __launch_bounds__(256) void convert_kernel(const void* __restrict__ src,
                                                      ushort_t* __restrict__ dst,
                                                      int n8, const int* flags) {
    int i = blockIdx.x * 256 + threadIdx.x;
    if (i >= n8) return;
    if (flags[0]) {
        const float4* s = (const float4*)src + (size_t)i * 2;
        float4 a = s[0], b = s[1];
        uint4 o;
        o.x = pk2(a.x, a.y); o.y = pk2(a.z, a.w);
        o.z = pk2(b.x, b.y); o.w = pk2(b.z, b.w);
        ((uint4*)dst)[i] = o;
    } else {
        ((uint4*)dst)[i] = ((const uint4*)src)[i];
    }
}

// ---------------- weight transpose (to bf16 W^T) ----------------
__global__ __launch_bounds__(256) void transpose_kernel(
    const void* W0, const void* W1, const void* W2, const void* W3, const void* W4,
    ushort_t* T0, ushort_t* T1, ushort_t* T2, ushort_t* T3, ushort_t* T4,
    const int* flags) {
    __shared__ float tl[32][33];
    int f32m = flags[0];
    const void* W; ushort_t* T;
    switch (blockIdx.z) {
        case 0: W = W0; T = T0; break;
        case 1: W = W1; T = T1; break;
        case 2: W = W2; T = T2; break;
        case 3: W = W3; T = T3; break;
        default: W = W4; T = T4; break;
    }
    int tx = threadIdx.x, ty = threadIdx.y;  // (32,8)
    int x = blockIdx.x * 32 + tx;
    #pragma unroll
    for (int j = 0; j < 4; ++j) {
        int row = blockIdx.y * 32 + ty + j * 8;
        tl[ty + j * 8][tx] = ldf(W, row * 1024 + x, f32m);
    }
    __syncthreads();
    #pragma unroll
    for (int j = 0; j < 4; ++j) {
        int n = blockIdx.x * 32 + ty + j * 8;
        T[n * 1024 + blockIdx.y * 32 + tx] = f2b(tl[tx][ty + j * 8]);
    }
}

// ---------------- V transpose: vh[bh][k][d] -> vT[bh][d][k] ----------------
__global__ __launch_bounds__(256) void vtrans_kernel(const ushort_t* __restrict__ vh,
                                                     ushort_t* __restrict__ vT) {
    __shared__ ushort_t t[64][68];
    int bh = blockIdx.y;
    int k0 = blockIdx.x * 64;
    int tid = threadIdx.x;
    int r = tid >> 2, c0 = (tid & 3) * 16;
    const short8* src = (const short8*)&vh[((size_t)bh * 1024 + k0 + r) * 64 + c0];
    *(short8*)&t[r][c0] = src[0];
    *(short8*)&t[r][c0 + 8] = src[1];
    __syncthreads();
    ushort_t tmp[16];
    #pragma unroll
    for (int j = 0; j < 16; ++j) tmp[j] = t[c0 + j][r];
    short8* dst = (short8*)&vT[((size_t)bh * 64 + r) * 1024 + k0 + c0];
    dst[0] = *(short8*)&tmp[0];
    dst[1] = *(short8*)&tmp[8];
}

// ---------------- projection GEMM (global_load_lds, linear LDS) ----------------
// EPI 0: qU/qV (adds bq then U/V, layout (b,h,q,d))
// EPI 1: k/v proj (adds bias, layout (b,h,kk,d))
// EPI 2: R proj (no bias, layout (h,j,d));  a_mode=1: A may be f32 (scalar staging)
// EPI 3: out proj (adds bias, writes d_out (q,b,e), dtype per flag)
template<int EPI>
__global__ __launch_bounds__(256) void gemm_kernel(
    const void* Av, const ushort_t* BT, int M,
    const void* bias, const void* Up, const void* Vp,
    void* out0, void* out1, const int* flags, int a_mode) {
    __shared__ ushort_t As[4096];
    __shared__ ushort_t Bs[4096];
    const int f32m = flags[0];
    const int a_f32 = a_mode ? f32m : 0;
    const int tid = threadIdx.x;
    const int wid = tid >> 6, lane = tid & 63;
    const int wr = (wid >> 1) * 64, wc = (wid & 1) * 64;
    const int m0 = blockIdx.x * 128, n0 = blockIdx.y * 128;
    const int ch0 = wid * 2;
    const int lrow = lane >> 2, lcol = (lane & 3) * 8;

    f32x4 acc[4][4];
    #pragma unroll
    for (int m = 0; m < 4; ++m)
        #pragma unroll
        for (int n = 0; n < 4; ++n)
            acc[m][n] = (f32x4){0.f, 0.f, 0.f, 0.f};

    for (int k0 = 0; k0 < 1024; k0 += 32) {
        if (a_f32) {
            const float* Af = (const float*)Av + (size_t)(m0 + (tid >> 1)) * 1024 + k0 + (tid & 1) * 16;
            ushort_t* dst = &As[(tid >> 1) * 32 + (tid & 1) * 16];
            #pragma unroll
            for (int e = 0; e < 16; ++e) dst[e] = f2b(Af[e]);
        } else {
            #pragma unroll
            for (int t = 0; t < 2; ++t) {
                int ch = ch0 + t;
                const ushort_t* ga = (const ushort_t*)Av + (size_t)(m0 + ch * 16 + lrow) * 1024 + k0 + lcol;
                __builtin_amdgcn_global_load_lds((async_src_t*)ga, (async_dst_t*)&As[ch * 512], 16, 0, 0);
            }
        }
        #pragma unroll
        for (int t = 0; t < 2; ++t) {
            int ch = ch0 + t;
            const ushort_t* gb = BT + (size_t)(n0 + ch * 16 + lrow) * 1024 + k0 + lcol;
            __builtin_amdgcn_global_load_lds((async_src_t*)gb, (async_dst_t*)&Bs[ch * 512], 16, 0, 0);
        }
        __syncthreads();

        short8 af[4], bf[4];
        #pragma unroll
        for (int m = 0; m < 4; ++m)
            af[m] = *(const short8*)&As[(wr + m * 16 + (lane & 15)) * 32 + (lane >> 4) * 8];
        #pragma unroll
        for (int n = 0; n < 4; ++n)
            bf[n] = *(const short8*)&Bs[(wc + n * 16 + (lane & 15)) * 32 + (lane >> 4) * 8];
        #pragma unroll
        for (int m = 0; m < 4; ++m)
            #pragma unroll
            for (int n = 0; n < 4; ++n)
                acc[m][n] = MFMA16(af[m], bf[n], acc[m][n]);
        __syncthreads();
    }

    #pragma unroll
    for (int n = 0; n < 4; ++n) {
        int gn = n0 + wc + n * 16 + (lane & 15);
        float bv_ = (EPI == 2) ? 0.f : ldf(bias, gn, f32m);
        float uu = 0.f, vv = 0.f;
        if (EPI == 0) { uu = ldf(Up, gn, f32m); vv = ldf(Vp, gn, f32m); }
        #pragma unroll
        for (int m = 0; m < 4; ++m) {
            #pragma unroll
            for (int j = 0; j < 4; ++j) {
                int gm = m0 + wr + m * 16 + (lane >> 4) * 4 + j;
                float c = acc[m][n][j] + bv_;
                if (EPI == 0) {
                    int q = gm >> 3, b = gm & 7;
                    int h = gn >> 6, d = gn & 63;
                    int idx = ((b * 16 + h) * 512 + q) * 64 + d;
                    ((ushort_t*)out0)[idx] = f2b(c + uu);
                    ((ushort_t*)out1)[idx] = f2b(c + vv);
                } else if (EPI == 1) {
                    int kk = gm >> 3, b = gm & 7;
                    int h = gn >> 6, d = gn & 63;
                    ((ushort_t*)out0)[((b * 16 + h) * 1024 + kk) * 64 + d] = f2b(c);
                } else if (EPI == 2) {
                    int h = gn >> 6, d = gn & 63;
                    ((ushort_t*)out0)[(h * 1024 + gm) * 64 + d] = f2b(c);
                } else {
                    if (f32m) ((float*)out0)[gm * 1024 + gn] = c;
                    else ((ushort_t*)out0)[gm * 1024 + gn] = f2b(c);
                }
            }
        }
    }
}

// ---------------- fused attention (32 q-rows/block, XCD-grouped, 8 waves) ----------------
// 1D grid 2048: xcd=d&7, qt=(d>>3)&15, bh=((d>>3)>>4)*8+xcd  -> all 16 q-tiles of a
// (b,h) land on one XCD so K/V/R stay L2-resident. Wave w owns k in [w*128, w*128+128).
// Lane: c = lane&15 = q-column within group, g = lane>>4. Two q-groups: q0+c, q0+16+c.
#define SP_STR 1032   // sPos row stride (ushorts): 516 words % 32 = 4 -> 2-way banks (free)
#define PB_STR 136    // sPb row stride (ushorts): 68 words % 32 = 4 -> 2-way banks (free)
__global__ __launch_bounds__(512, 4) void attn_kernel(
    const ushort_t* __restrict__ qU, const ushort_t* __restrict__ qV,
    const ushort_t* __restrict__ kh, const ushort_t* __restrict__ vT,
    const ushort_t* __restrict__ Rl, const void* __restrict__ mask,
    const void* __restrict__ pad, ushort_t* __restrict__ alpha, const int* flags) {

    // union region: sPos [33][1032] u16 (68,112 B) | sPb [8][32][136] u16 (69,632 B)
    //             | sO [8][64][33] f32 (67,584 B). Aliasing is barrier-separated.
    __shared__ __align__(16) uchar_t uni[69632];
    ushort_t* sPos = (ushort_t*)uni;
    ushort_t* sPb  = (ushort_t*)uni;
    float*    sO   = (float*)uni;
    __shared__ float spad[512];
    __shared__ float sred[2][8][32];
    __shared__ float ssinv[32];

    const int tid = threadIdx.x;
    const int wid = tid >> 6, lane = tid & 63;
    const int g = lane >> 4, c = lane & 15;
    const int dix = blockIdx.x;
    const int xcd = dix & 7;
    const int tt = dix >> 3;
    const int qt = tt & 15;
    const int bh = ((tt >> 4) << 3) | xcd;
    const int q0 = qt * 32;
    const int b = bh >> 4, h = bh & 15;
    const int f32m = flags[0], mm = flags[1];
    const int kbase = wid * 128;

    spad[tid & 511] = ldf(pad, b * 512 + (tid & 511), f32m);

    // ---- position: PR^T[j][q] = R[j] . qV[q] for q-rows q0..q0+32 -> sPos (bf16)
    {
        const ushort_t* qva = qV + ((size_t)bh * 512 + q0 + c) * 64 + g * 8;
        short8 a0 = *(const short8*)qva;
        short8 a1 = *(const short8*)(qva + 32);
        const ushort_t* qvb = qV + ((size_t)bh * 512 + q0 + 16 + c) * 64 + g * 8;
        short8 b0 = *(const short8*)qvb;
        short8 b1 = *(const short8*)(qvb + 32);
        int qcc = q0 + 32 + c; if (qcc > 511) qcc = 511;   // clamp; clamped value never read
        const ushort_t* qvc = qV + ((size_t)bh * 512 + qcc) * 64 + g * 8;
        short8 c0_ = *(const short8*)qvc;
        short8 c1_ = *(const short8*)(qvc + 32);
        #pragma unroll
        for (int m = 0; m < 8; ++m) {
            const ushort_t* rp = Rl + ((size_t)h * 1024 + kbase + m * 16 + c) * 64 + g * 8;
            short8 ra0 = *(const short8*)rp;
            short8 ra1 = *(const short8*)(rp + 32);
            f32x4 p0 = (f32x4){0.f, 0.f, 0.f, 0.f};
            p0 = MFMA16(ra0, a0, p0);
            p0 = MFMA16(ra1, a1, p0);
            f32x4 p1 = (f32x4){0.f, 0.f, 0.f, 0.f};
            p1 = MFMA16(ra0, b0, p1);
            p1 = MFMA16(ra1, b1, p1);
            uint2 w0, w1;
            w0.x = pk2(p0[0], p0[1]); w0.y = pk2(p0[2], p0[3]);
            w1.x = pk2(p1[0], p1[1]); w1.y = pk2(p1[2], p1[3]);
            *(uint2*)&sPos[c * SP_STR + kbase + m * 16 + g * 4] = w0;
            *(uint2*)&sPos[(16 + c) * SP_STR + kbase + m * 16 + g * 4] = w1;
            f32x4 p2 = (f32x4){0.f, 0.f, 0.f, 0.f};
            p2 = MFMA16(ra0, c0_, p2);
            p2 = MFMA16(ra1, c1_, p2);
            if (c == 0) {
                uint2 w2;
                w2.x = pk2(p2[0], p2[1]); w2.y = pk2(p2[2], p2[3]);
                *(uint2*)&sPos[32 * SP_STR + kbase + m * 16 + g * 4] = w2;
            }
        }
    }

    // ---- content: S^T[k][q] = K[k] . qU[q] for both q-groups
    f32x4 acc[16];   // acc[m]=group0, acc[8+m]=group1
    {
        const ushort_t* qua = qU + ((size_t)bh * 512 + q0 + c) * 64 + g * 8;
        short8 bu0a = *(const short8*)qua;
        short8 bu1a = *(const short8*)(qua + 32);
        const ushort_t* qub = qU + ((size_t)bh * 512 + q0 + 16 + c) * 64 + g * 8;
        short8 bu0b = *(const short8*)qub;
        short8 bu1b = *(const short8*)(qub + 32);
        #pragma unroll
        for (int m = 0; m < 8; ++m) {
            const ushort_t* kp = kh + ((size_t)bh * 1024 + kbase + m * 16 + c) * 64 + g * 8;
            short8 ka0 = *(const short8*)kp;
            short8 ka1 = *(const short8*)(kp + 32);
            f32x4 t0 = (f32x4){0.f, 0.f, 0.f, 0.f};
            t0 = MFMA16(ka0, bu0a, t0);
            t0 = MFMA16(ka1, bu1a, t0);
            acc[m] = t0;
            f32x4 t1 = (f32x4){0.f, 0.f, 0.f, 0.f};
            t1 = MFMA16(ka0, bu0b, t1);
            t1 = MFMA16(ka1, bu1b, t1);
            acc[8 + m] = t1;
        }
    }
    __syncthreads();

    // ---- score: rel-shifted position gather + masks + scale (per q-group)
    float mx0 = -3.0e38f, mx1 = -3.0e38f;
    #pragma unroll
    for (int gt = 0; gt < 2; ++gt) {
        const int q = q0 + 16 * gt + c;
        const float padq = spad[q];
        float mxl = -3.0e38f;
        #pragma unroll
        for (int m = 0; m < 8; ++m) {
            int k0e = kbase + m * 16 + g * 4;
            uint_t mb[4];
            if (mm == 1) {
                uint_t w = *(const uint_t*)((const uchar_t*)mask + (size_t)q * 1024 + k0e);
                mb[0] = w & 0xFFu; mb[1] = w & 0xFF00u; mb[2] = w & 0xFF0000u; mb[3] = w & 0xFF000000u;
            } else if (mm == 2) {
                uint2 w = *(const uint2*)((const ushort_t*)mask + (size_t)q * 1024 + k0e);
                mb[0] = w.x & 0xFFFFu; mb[1] = w.x >> 16; mb[2] = w.y & 0xFFFFu; mb[3] = w.y >> 16;
            } else {
                uint4 w = *(const uint4*)((const uint_t*)mask + (size_t)q * 1024 + k0e);
                mb[0] = w.x; mb[1] = w.y; mb[2] = w.z; mb[3] = w.w;
            }
            #pragma unroll
            for (int jj = 0; jj < 4; ++jj) {
                int k = k0e + jj;
                int delta = k - q;
                int wrap = (delta > 512) ? 1 : 0;
                int j = wrap ? (delta - 514) : (delta + 511);
                float pos = b2f(sPos[(16 * gt + c + wrap) * SP_STR + (j < 0 ? 0 : j)]);
                if (delta == 513) pos = 0.f;
                float s = (acc[8 * gt + m][jj] + pos) * 0.03125f;
                bool dead = (mb[jj] != 0);
                if (k >= 512) {
                    float padk = spad[k - 512];
                    if (padq == 0.f || padk == 0.f) dead = true;
                }
                if (dead) s = -1e20f;
                acc[8 * gt + m][jj] = s;
                mxl = fmaxf(mxl, s);
            }
        }
        if (gt == 0) mx0 = mxl; else mx1 = mxl;
    }
    // row-max: lanes sharing q are xor-16/32 apart; then cross-wave
    mx0 = fmaxf(mx0, __shfl_xor(mx0, 16, 64));
    mx0 = fmaxf(mx0, __shfl_xor(mx0, 32, 64));
    mx1 = fmaxf(mx1, __shfl_xor(mx1, 16, 64));
    mx1 = fmaxf(mx1, __shfl_xor(mx1, 32, 64));
    if (lane < 16) { sred[0][wid][c] = mx0; sred[0][wid][16 + c] = mx1; }
    __syncthreads();   // also: all sPos reads complete before sPb overlays it
    {
        float a0 = fmaxf(fmaxf(sred[0][0][c], sred[0][1][c]), fmaxf(sred[0][2][c], sred[0][3][c]));
        float a1 = fmaxf(fmaxf(sred[0][4][c], sred[0][5][c]), fmaxf(sred[0][6][c], sred[0][7][c]));
        mx0 = fmaxf(a0, a1);
        float b0r = fmaxf(fmaxf(sred[0][0][16 + c], sred[0][1][16 + c]), fmaxf(sred[0][2][16 + c], sred[0][3][16 + c]));
        float b1r = fmaxf(fmaxf(sred[0][4][16 + c], sred[0][5][16 + c]), fmaxf(sred[0][6][16 + c], sred[0][7][16 + c]));
        mx1 = fmaxf(b0r, b1r);
    }

    // ---- exp + pack P (bf16) into per-wave LDS tile sPb[wid*32 + qlocal][k_local]
    float ls0 = 0.f, ls1 = 0.f;
    #pragma unroll
    for (int gt = 0; gt < 2; ++gt) {
        float mxl = gt ? mx1 : mx0;
        float lsl = 0.f;
        #pragma unroll
        for (int m = 0; m < 8; ++m) {
            float p0 = __expf(acc[8 * gt + m][0] - mxl);
            float p1 = __expf(acc[8 * gt + m][1] - mxl);
            float p2 = __expf(acc[8 * gt + m][2] - mxl);
            float p3 = __expf(acc[8 * gt + m][3] - mxl);
            lsl += (p0 + p1) + (p2 + p3);
            uint2 w;
            w.x = pk2(p0, p1);
            w.y = pk2(p2, p3);
            *(uint2*)&sPb[(wid * 32 + 16 * gt + c) * PB_STR + m * 16 + g * 4] = w;
        }
        if (gt == 0) ls0 = lsl; else ls1 = lsl;
    }
    ls0 += __shfl_xor(ls0, 16, 64);
    ls0 += __shfl_xor(ls0, 32, 64);
    ls1 += __shfl_xor(ls1, 16, 64);
    ls1 += __shfl_xor(ls1, 32, 64);
    if (lane < 16) { sred[1][wid][c] = ls0; sred[1][wid][16 + c] = ls1; }

    // ---- PV: prefetch ALL V loads while the ls-barrier settles
    short8 va[4][4];
    #pragma unroll
    for (int ch = 0; ch < 4; ++ch)
        #pragma unroll
        for (int dm = 0; dm < 4; ++dm)
            va[ch][dm] = *(const short8*)(vT + ((size_t)bh * 64 + dm * 16 + c) * 1024 + kbase + ch * 32 + g * 8);
    __syncthreads();   // sPb writes visible; all waves' P staged
    {
        float a0 = (sred[1][0][c] + sred[1][1][c]) + (sred[1][2][c] + sred[1][3][c]);
        float a1 = (sred[1][4][c] + sred[1][5][c]) + (sred[1][6][c] + sred[1][7][c]);
        ls0 = a0 + a1;
        float b0r = (sred[1][0][16 + c] + sred[1][1][16 + c]) + (sred[1][2][16 + c] + sred[1][3][16 + c]);
        float b1r = (sred[1][4][16 + c] + sred[1][5][16 + c]) + (sred[1][6][16 + c] + sred[1][7][16 + c]);
        ls1 = b0r + b1r;
    }
    if (wid == 0 && lane < 16) { ssinv[c] = 1.0f / ls0; ssinv[16 + c] = 1.0f / ls1; }

    f32x4 oacc0[4], oacc1[4];
    #pragma unroll
    for (int dm = 0; dm < 4; ++dm) {
        oacc0[dm] = (f32x4){0.f, 0.f, 0.f, 0.f};
        oacc1[dm] = (f32x4){0.f, 0.f, 0.f, 0.f};
    }
    #pragma unroll
    for (int ch = 0; ch < 4; ++ch) {
        short8 pb0 = *(const short8*)&sPb[(wid * 32 + c) * PB_STR + ch * 32 + g * 8];
        short8 pb1 = *(const short8*)&sPb[(wid * 32 + 16 + c) * PB_STR + ch * 32 + g * 8];
        #pragma unroll
        for (int dm = 0; dm < 4; ++dm) {
            oacc0[dm] = MFMA16(va[ch][dm], pb0, oacc0[dm]);
            oacc1[dm] = MFMA16(va[ch][dm], pb1, oacc1[dm]);
        }
    }

    // cross-wave O reduction (overlay sO on union region; PV sPb reads done)
    __syncthreads();
    #pragma unroll
    for (int dm = 0; dm < 4; ++dm)
        #pragma unroll
        for (int jj = 0; jj < 4; ++jj) {
            sO[wid * 2112 + (dm * 16 + g * 4 + jj) * 33 + c] = oacc0[dm][jj];
            sO[wid * 2112 + (dm * 16 + g * 4 + jj) * 33 + 16 + c] = oacc1[dm][jj];
        }
    __syncthreads();
    for (int e = tid; e < 2048; e += 512) {
        int d = e & 63, qq = e >> 6;
        float v = ((sO[d * 33 + qq] + sO[2112 + d * 33 + qq]) +
                   (sO[4224 + d * 33 + qq] + sO[6336 + d * 33 + qq])) +
                  ((sO[8448 + d * 33 + qq] + sO[10560 + d * 33 + qq]) +
                   (sO[12672 + d * 33 + qq] + sO[14784 + d * 33 + qq]));
        v *= ssinv[qq];
        alpha[((size_t)(q0 + qq) * 8 + b) * 1024 + h * 64 + d] = f2b(v);
    }
}

// ---------------- launcher ----------------
// Workspace: EXACTLY 88,081,408 bytes (round-3/6..9 proven footprint), r7 alias scheme.
extern "C" void kernel_launch(void* const* d_in, const int* in_sizes, int n_in,
                              void* d_out, int out_size, void* d_ws, size_t ws_size,
                              hipStream_t stream) {
    char* ws = (char*)d_ws;
    int* flags = (int*)ws;
    ushort_t* WqT   = (ushort_t*)(ws + 1024);
    ushort_t* WkT   = WqT + 1048576;
    ushort_t* WvT   = WkT + 1048576;
    ushort_t* WposT = WvT + 1048576;
    ushort_t* WoT   = WposT + 1048576;
    ushort_t* qUw   = WoT + 1048576;            // 4,194,304
    ushort_t* qVw   = qUw + 4194304;            // 4,194,304
    ushort_t* khw   = qVw + 4194304;            // 8,388,608
    ushort_t* Rlw   = khw + 8388608;            // 1,048,576
    ushort_t* R1    = Rlw + 1048576;            // 4,194,304
    ushort_t* R2    = R1 + 4194304;             // 8,388,608
    ushort_t* R3    = R2 + 8388608;             // 8,388,608
    // aliases (lifetime-disjoint, stream-ordered):
    ushort_t* qbf = R1;     // convert out -> read by qGEMM -> dead
    ushort_t* alw = R1;     // attn out -> read by outGEMM
    ushort_t* kbf = R2;     // convert out -> read by kGEMM -> dead
    ushort_t* vhw = R2;     // vGEMM out -> read by vtrans -> dead
    ushort_t* vbf = R3;     // convert out -> read by vGEMM -> dead
    ushort_t* vTw = R3;     // vtrans out -> read by attn

    detect_kernel<<<1, 256, 0, stream>>>(d_in[6], d_in[7], flags);
    // bulk input conversion to bf16 (query, key, value)
    convert_kernel<<<2048, 256, 0, stream>>>(d_in[0], qbf, 524288, flags);
    convert_kernel<<<4096, 256, 0, stream>>>(d_in[1], kbf, 1048576, flags);
    convert_kernel<<<4096, 256, 0, stream>>>(d_in[2], vbf, 1048576, flags);
    // weight transposes
    transpose_kernel<<<dim3(32, 32, 5), dim3(32, 8), 0, stream>>>(
        d_in[8], d_in[10], d_in[12], d_in[14], d_in[15],
        WqT, WkT, WvT, WposT, WoT, flags);
    // q projection -> qU, qV (fast A path)
    gemm_kernel<0><<<dim3(32, 8), 256, 0, stream>>>(qbf, WqT, 4096, d_in[9], d_in[4], d_in[5], qUw, qVw, flags, 0);
    // k, v projections (fast A path)
    gemm_kernel<1><<<dim3(64, 8), 256, 0, stream>>>(kbf, WkT, 8192, d_in[11], nullptr, nullptr, khw, nullptr, flags, 0);
    gemm_kernel<1><<<dim3(64, 8), 256, 0, stream>>>(vbf, WvT, 8192, d_in[13], nullptr, nullptr, vhw, nullptr, flags, 0);
    // R projection (raw pos_embedding, scalar-convert staging when f32)
    gemm_kernel<2><<<dim3(8, 8), 256, 0, stream>>>(d_in[3], WposT, 1024, nullptr, nullptr, nullptr, Rlw, nullptr, flags, 1);
    // V transpose for PV A-operand: R2 -> R3
    vtrans_kernel<<<dim3(16, 128), 256, 0, stream>>>(vhw, vTw);
    // fused attention (32 q/block, XCD-grouped 1D grid)
    attn_kernel<<<dim3(2048), 512, 0, stream>>>(qUw, qVw, khw, vTw, Rlw, d_in[6], d_in[7], alw, flags);
    // output projection
    gemm_kernel<3><<<dim3(32, 8), 256, 0, stream>>>(alw, WoT, 4096, d_in[16], nullptr, nullptr, d_out, nullptr, flags, 0);
}

// Round 11
// 347.501 us; speedup vs baseline: 1.2676x; 1.2676x over previous
//
#include <hip/hip_runtime.h>

#define QLEN 512
#define KLEN 1024
#define BATCH 8
#define HEADS 16
#define HDIM 64
#define EMBED 1024

typedef __attribute__((ext_vector_type(4))) float f32x4;
typedef __attribute__((ext_vector_type(8))) short short8;
typedef unsigned short ushort_t;
typedef unsigned char uchar_t;
typedef unsigned int uint_t;

#define MFMA16(a, b, c) __builtin_amdgcn_mfma_f32_16x16x32_bf16((a), (b), (c), 0, 0, 0)

__device__ __forceinline__ float b2f(ushort_t u) {
    union { uint_t i; float f; } c; c.i = ((uint_t)u) << 16; return c.f;
}
__device__ __forceinline__ ushort_t f2b(float x) {
    union { float f; uint_t i; } c; c.f = x;
    uint_t u = c.i;
    uint_t r = (u + 0x7FFFu + ((u >> 16) & 1u)) >> 16;
    return (ushort_t)r;
}
__device__ __forceinline__ uint_t pk2(float lo, float hi) {
    return (uint_t)f2b(lo) | ((uint_t)f2b(hi) << 16);
}
// load a "float" that may be stored as f32 or bf16
__device__ __forceinline__ float ldf(const void* p, int idx, int f32m) {
    if (f32m) return ((const float*)p)[idx];
    return b2f(((const ushort_t*)p)[idx]);
}

typedef const __attribute__((address_space(1))) void async_src_t;
typedef __attribute__((address_space(3))) void async_dst_t;

// ---------------- dtype detector ----------------
// flags[0]: 1 if float tensors are f32, 0 if bf16
// flags[1]: mask mode: 0=int32, 1=uint8, 2=bf16, 3=f32
__global__ __launch_bounds__(256) void detect_kernel(const void* mask, const void* pad, int* flags) {
    __shared__ int cnt[4];
    int tid = threadIdx.x;
    if (tid < 4) cnt[tid] = 0;
    __syncthreads();
    const uchar_t* mb = (const uchar_t*)mask;
    const uchar_t* pb = (const uchar_t*)pad;
    int lnz1 = 0, l3f1 = 0, l3f3 = 0, lpnz = 0;
    for (int off = tid; off < 4096; off += 256) {
        uchar_t v = mb[off];
        int m4 = off & 3;
        if (m4 != 0 && v != 0) lnz1++;
        if (m4 == 1 && v == 0x3F) l3f1++;
        if (m4 == 3 && v == 0x3F) l3f3++;
        uchar_t p = pb[off];
        if (m4 == 0 && p != 0) lpnz++;
    }
    atomicAdd(&cnt[0], lnz1); atomicAdd(&cnt[1], l3f1);
    atomicAdd(&cnt[2], l3f3); atomicAdd(&cnt[3], lpnz);
    __syncthreads();
    if (tid == 0) {
        flags[0] = (cnt[3] == 0) ? 1 : 0;
        int mm;
        if (cnt[0] == 0) mm = 0;
        else if (cnt[1] > 16) mm = 2;
        else if (cnt[2] > 16) mm = 3;
        else mm = 1;
        flags[1] = mm;
    }
}

// ---------------- bulk convert to bf16 ----------------
__global__ __launch_bounds__(256) void convert_kernel(const void* __restrict__ src,
                                                      ushort_t* __restrict__ dst,
                                                      int n8, const int* flags) {
    int i = blockIdx.x * 256 + threadIdx.x;
    if (i >= n8) return;
    if (flags[0]) {
        const float4* s = (const float4*)src + (size_t)i * 2;
        float4 a = s[0], b = s[1];
        uint4 o;
        o.x = pk2(a.x, a.y); o.y = pk2(a.z, a.w);
        o.z = pk2(b.x, b.y); o.w = pk2(b.z, b.w);
        ((uint4*)dst)[i] = o;
    } else {
        ((uint4*)dst)[i] = ((const uint4*)src)[i];
    }
}

// ---------------- mask+padding prepack: dead-bit per (b,q,k), layout [b][w4][q][w&3] ----------------
__global__ __launch_bounds__(256) void maskprep_kernel(const void* __restrict__ mask,
                                                       const void* __restrict__ pad,
                                                       uint_t* __restrict__ bits,
                                                       const int* flags) {
    int tid = blockIdx.x * 256 + threadIdx.x;   // 8*512*32 = 131072 threads
    int w = tid & 31, q = (tid >> 5) & 511, b = tid >> 14;
    int mm = flags[1], f32m = flags[0];
    float padq = ldf(pad, b * 512 + q, f32m);
    uint_t word = 0;
    for (int j = 0; j < 32; ++j) {
        int k = w * 32 + j;
        size_t mi = (size_t)q * 1024 + k;
        int dead;
        if (mm == 1) dead = (((const uchar_t*)mask)[mi] != 0);
        else if (mm == 2) dead = (((const ushort_t*)mask)[mi] != 0);
        else dead = (((const uint_t*)mask)[mi] != 0);
        if (k >= 512) {
            float padk = ldf(pad, b * 512 + k - 512, f32m);
            if (padq == 0.f || padk == 0.f) dead = 1;
        }
        word |= ((uint_t)dead) << j;
    }
    // transposed layout: [b][w>>2][q][w&3] so attn's uint4 read is q-contiguous
    bits[((b * 8 + (w >> 2)) * 512 + q) * 4 + (w & 3)] = word;
}

// ---------------- weight transpose (to bf16 W^T) ----------------
__global__ __launch_bounds__(256) void transpose_kernel(
    const void* W0, const void* W1, const void* W2, const void* W3, const void* W4,
    ushort_t* T0, ushort_t* T1, ushort_t* T2, ushort_t* T3, ushort_t* T4,
    const int* flags) {
    __shared__ float tl[32][33];
    int f32m = flags[0];
    const void* W; ushort_t* T;
    switch (blockIdx.z) {
        case 0: W = W0; T = T0; break;
        case 1: W = W1; T = T1; break;
        case 2: W = W2; T = T2; break;
        case 3: W = W3; T = T3; break;
        default: W = W4; T = T4; break;
    }
    int tx = threadIdx.x, ty = threadIdx.y;  // (32,8)
    int x = blockIdx.x * 32 + tx;
    #pragma unroll
    for (int j = 0; j < 4; ++j) {
        int row = blockIdx.y * 32 + ty + j * 8;
        tl[ty + j * 8][tx] = ldf(W, row * 1024 + x, f32m);
    }
    __syncthreads();
    #pragma unroll
    for (int j = 0; j < 4; ++j) {
        int n = blockIdx.x * 32 + ty + j * 8;
        T[n * 1024 + blockIdx.y * 32 + tx] = f2b(tl[tx][ty + j * 8]);
    }
}

// ---------------- V transpose to fragment-native tiles ----------------
// in : vh[bh][k][d]   (b,h,k,d) from v-GEMM
// out: chunk16B idx = (((bh*8 + kc)*4 + ch)*4 + dm)*64 + c*4 + g ; elements = k-octet
//      where k = kc*128 + ch*32 + g*8 + e, d = dm*16 + c
__global__ __launch_bounds__(256) void vtrans_kernel(const ushort_t* __restrict__ vh,
                                                     ushort_t* __restrict__ vT) {
    __shared__ ushort_t t[64][68];
    int bh = blockIdx.y;
    int k0 = blockIdx.x * 64;
    int tid = threadIdx.x;
    int r = tid >> 2, c0 = (tid & 3) * 16;
    const short8* src = (const short8*)&vh[((size_t)bh * 1024 + k0 + r) * 64 + c0];
    *(short8*)&t[r][c0] = src[0];
    *(short8*)&t[r][c0 + 8] = src[1];
    __syncthreads();
    ushort_t tmp[16];
    #pragma unroll
    for (int j = 0; j < 16; ++j) tmp[j] = t[c0 + j][r];
    int dm = r >> 4, cc = r & 15;
    #pragma unroll
    for (int tt = 0; tt < 2; ++tt) {
        int og = ((k0 + c0) >> 3) + tt;
        int kc = og >> 4, ch = (og >> 2) & 3, g = og & 3;
        size_t addr = ((((((size_t)bh * 8 + kc) * 4 + ch) * 4 + dm) * 64) + cc * 4 + g) * 8;
        *(short8*)&vT[addr] = *(short8*)&tmp[tt * 8];
    }
}

// ---------------- projection GEMM (global_load_lds, linear LDS) ----------------
// EPI 0: qU/qV, fragment-native: chunk=(bhk*32+qt)*128 + half*64 + c*4+g (elem=d&7)
// EPI 1: v proj, old (b,h,k,d) layout (vtrans input)
// EPI 2: R proj, fragment-native: chunk=((h*8+kc)*8+m)*2+half)*64 + c*4+g
// EPI 3: out proj (adds bias, writes d_out (q,b,e), dtype per flag)
// EPI 4: k proj, fragment-native: chunk=(((bhk*8+kc)*8+m)*2+half)*64 + c*4+g
template<int EPI>
__global__ __launch_bounds__(256) void gemm_kernel(
    const void* Av, const ushort_t* BT, int M,
    const void* bias, const void* Up, const void* Vp,
    void* out0, void* out1, const int* flags, int a_mode) {
    __shared__ ushort_t As[4096];
    __shared__ ushort_t Bs[4096];
    const int f32m = flags[0];
    const int a_f32 = a_mode ? f32m : 0;
    const int tid = threadIdx.x;
    const int wid = tid >> 6, lane = tid & 63;
    const int wr = (wid >> 1) * 64, wc = (wid & 1) * 64;
    const int m0 = blockIdx.x * 128, n0 = blockIdx.y * 128;
    const int ch0 = wid * 2;
    const int lrow = lane >> 2, lcol = (lane & 3) * 8;

    f32x4 acc[4][4];
    #pragma unroll
    for (int m = 0; m < 4; ++m)
        #pragma unroll
        for (int n = 0; n < 4; ++n)
            acc[m][n] = (f32x4){0.f, 0.f, 0.f, 0.f};

    for (int k0 = 0; k0 < 1024; k0 += 32) {
        if (a_f32) {
            const float* Af = (const float*)Av + (size_t)(m0 + (tid >> 1)) * 1024 + k0 + (tid & 1) * 16;
            ushort_t* dst = &As[(tid >> 1) * 32 + (tid & 1) * 16];
            #pragma unroll
            for (int e = 0; e < 16; ++e) dst[e] = f2b(Af[e]);
        } else {
            #pragma unroll
            for (int t = 0; t < 2; ++t) {
                int ch = ch0 + t;
                const ushort_t* ga = (const ushort_t*)Av + (size_t)(m0 + ch * 16 + lrow) * 1024 + k0 + lcol;
                __builtin_amdgcn_global_load_lds((async_src_t*)ga, (async_dst_t*)&As[ch * 512], 16, 0, 0);
            }
        }
        #pragma unroll
        for (int t = 0; t < 2; ++t) {
            int ch = ch0 + t;
            const ushort_t* gb = BT + (size_t)(n0 + ch * 16 + lrow) * 1024 + k0 + lcol;
            __builtin_amdgcn_global_load_lds((async_src_t*)gb, (async_dst_t*)&Bs[ch * 512], 16, 0, 0);
        }
        __syncthreads();

        short8 af[4], bf[4];
        #pragma unroll
        for (int m = 0; m < 4; ++m)
            af[m] = *(const short8*)&As[(wr + m * 16 + (lane & 15)) * 32 + (lane >> 4) * 8];
        #pragma unroll
        for (int n = 0; n < 4; ++n)
            bf[n] = *(const short8*)&Bs[(wc + n * 16 + (lane & 15)) * 32 + (lane >> 4) * 8];
        #pragma unroll
        for (int m = 0; m < 4; ++m)
            #pragma unroll
            for (int n = 0; n < 4; ++n)
                acc[m][n] = MFMA16(af[m], bf[n], acc[m][n]);
        __syncthreads();
    }

    #pragma unroll
    for (int n = 0; n < 4; ++n) {
        int gn = n0 + wc + n * 16 + (lane & 15);
        float bv_ = (EPI == 2) ? 0.f : ldf(bias, gn, f32m);
        float uu = 0.f, vv = 0.f;
        if (EPI == 0) { uu = ldf(Up, gn, f32m); vv = ldf(Vp, gn, f32m); }
        #pragma unroll
        for (int m = 0; m < 4; ++m) {
            #pragma unroll
            for (int j = 0; j < 4; ++j) {
                int gm = m0 + wr + m * 16 + (lane >> 4) * 4 + j;
                float c = acc[m][n][j] + bv_;
                if (EPI == 0) {
                    int q = gm >> 3, b = gm & 7;
                    int h = gn >> 6, d = gn & 63;
                    int bhk = b * 16 + h;
                    size_t addr = ((size_t)bhk * 32 + (q >> 4)) * 1024 + (size_t)(d >> 5) * 512
                                  + ((q & 15) * 4 + ((d >> 3) & 3)) * 8 + (d & 7);
                    ((ushort_t*)out0)[addr] = f2b(c + uu);
                    ((ushort_t*)out1)[addr] = f2b(c + vv);
                } else if (EPI == 1) {
                    int kk = gm >> 3, b = gm & 7;
                    int h = gn >> 6, d = gn & 63;
                    ((ushort_t*)out0)[((b * 16 + h) * 1024 + kk) * 64 + d] = f2b(c);
                } else if (EPI == 2) {
                    int h = gn >> 6, d = gn & 63;
                    int jr = gm;
                    size_t addr = (((((size_t)h * 8 + (jr >> 7)) * 8 + ((jr >> 4) & 7)) * 2 + (d >> 5)) * 64
                                   + ((jr & 15) * 4 + ((d >> 3) & 3))) * 8 + (d & 7);
                    ((ushort_t*)out0)[addr] = f2b(c);
                } else if (EPI == 4) {
                    int kk = gm >> 3, b = gm & 7;
                    int h = gn >> 6, d = gn & 63;
                    size_t addr = ((((((size_t)(b * 16 + h)) * 8 + (kk >> 7)) * 8 + ((kk >> 4) & 7)) * 2 + (d >> 5)) * 64
                                   + ((kk & 15) * 4 + ((d >> 3) & 3))) * 8 + (d & 7);
                    ((ushort_t*)out0)[addr] = f2b(c);
                } else {
                    if (f32m) ((float*)out0)[gm * 1024 + gn] = c;
                    else ((ushort_t*)out0)[gm * 1024 + gn] = f2b(c);
                }
            }
        }
    }
}

// ---------------- fused attention (fragment-native coalesced loads, 8 waves) ----------------
// block: 16 q-rows x one (b,h); 8 waves, wave w owns k in [w*128, w*128+128)
// Lane: c = lane&15 = q-column, g = lane>>4. S^T C-layout: col=c(q), row=k-local.
// All operand loads read 1KB contiguous per instruction (chunk idx = c*4+g).
#define SP_STR 1032   // sPos row stride (ushorts): 516 words % 32 = 4 -> 2-way banks (free)
#define PB_STR 136    // sPb row stride (ushorts): 68 words % 32 = 4 -> 2-way banks (free)
__global__ __launch_bounds__(512, 4) void attn_kernel(
    const ushort_t* __restrict__ qU, const ushort_t* __restrict__ qV,
    const ushort_t* __restrict__ khn, const ushort_t* __restrict__ vtn,
    const ushort_t* __restrict__ Rln, const uint_t* __restrict__ mbits,
    ushort_t* __restrict__ alpha) {

    // union region: sPos [17][1032] u16 (35,088 B) | sPb [8][16][136] u16 (34,816 B)
    //             | sO [8][1088] f32 (34,816 B). Aliasing is barrier-separated.
    __shared__ __align__(16) uchar_t uni[35104];
    ushort_t* sPos = (ushort_t*)uni;
    ushort_t* sPb  = (ushort_t*)uni;
    float*    sO   = (float*)uni;
    __shared__ float sred[2][8][16];
    __shared__ float ssinv[16];

    const int tid = threadIdx.x;
    const int wid = tid >> 6, lane = tid & 63;
    const int g = lane >> 4, c = lane & 15;
    const int qt = blockIdx.x;
    const int q0 = qt * 16;
    const int bh = blockIdx.y;
    const int b = bh >> 4, h = bh & 15;
    const int kbase = wid * 128;
    const int lch = (c * 4 + g) * 8;   // ushort offset of this lane's 16B chunk

    // ---- position: PR^T[j][q] = R[j] . qV[q];  write PR[q][j] (bf16) to sPos
    {
        size_t qvb = ((size_t)bh * 32 + qt) * 1024;
        short8 bva0 = *(const short8*)&qV[qvb + lch];
        short8 bva1 = *(const short8*)&qV[qvb + 512 + lch];
        int qtb = (qt == 31) ? 31 : qt + 1;
        int cb = (qt == 31) ? 15 : c;
        size_t qvb2 = ((size_t)bh * 32 + qtb) * 1024;
        short8 bvb0 = *(const short8*)&qV[qvb2 + (cb * 4 + g) * 8];
        short8 bvb1 = *(const short8*)&qV[qvb2 + 512 + (cb * 4 + g) * 8];
        #pragma unroll
        for (int m = 0; m < 8; ++m) {
            size_t rb = ((((size_t)h * 8 + wid) * 8 + m) * 2) * 512;
            short8 ra0 = *(const short8*)&Rln[rb + lch];
            short8 ra1 = *(const short8*)&Rln[rb + 512 + lch];
            f32x4 p0 = (f32x4){0.f, 0.f, 0.f, 0.f};
            p0 = MFMA16(ra0, bva0, p0);
            p0 = MFMA16(ra1, bva1, p0);
            f32x4 p1 = (f32x4){0.f, 0.f, 0.f, 0.f};
            p1 = MFMA16(ra0, bvb0, p1);
            p1 = MFMA16(ra1, bvb1, p1);
            uint2 w;
            w.x = pk2(p0[0], p0[1]);
            w.y = pk2(p0[2], p0[3]);
            *(uint2*)&sPos[c * SP_STR + kbase + m * 16 + g * 4] = w;
            if (c == 0) {
                uint2 x;
                x.x = pk2(p1[0], p1[1]);
                x.y = pk2(p1[2], p1[3]);
                *(uint2*)&sPos[16 * SP_STR + kbase + m * 16 + g * 4] = x;
            }
        }
    }

    // ---- content: S^T[k][q] = K[k] . qU[q]
    f32x4 acc[8];
    {
        size_t qub = ((size_t)bh * 32 + qt) * 1024;
        short8 bu0 = *(const short8*)&qU[qub + lch];
        short8 bu1 = *(const short8*)&qU[qub + 512 + lch];
        #pragma unroll
        for (int m = 0; m < 8; ++m) {
            size_t kb = ((((size_t)bh * 8 + wid) * 8 + m) * 2) * 512;
            short8 ka0 = *(const short8*)&khn[kb + lch];
            short8 ka1 = *(const short8*)&khn[kb + 512 + lch];
            f32x4 t = (f32x4){0.f, 0.f, 0.f, 0.f};
            t = MFMA16(ka0, bu0, t);
            t = MFMA16(ka1, bu1, t);
            acc[m] = t;
        }
    }
    __syncthreads();

    // ---- mask bits: one coalesced uint4 per thread (128 k-bits = this wave's range)
    const int q = q0 + c;
    uint4 mw = *(const uint4*)(mbits + ((size_t)(b * 8 + wid) * 512 + q) * 4);
    uint_t mwa[4] = {mw.x, mw.y, mw.z, mw.w};

    // ---- score: add rel-shifted position (sPos gather), scale, mask bits
    float mx = -3.0e38f;
    #pragma unroll
    for (int m = 0; m < 8; ++m) {
        int k0e = kbase + m * 16 + g * 4;
        uint_t word = mwa[m >> 1];
        #pragma unroll
        for (int jj = 0; jj < 4; ++jj) {
            int k = k0e + jj;
            int delta = k - q;
            int wrap = (delta > 512) ? 1 : 0;
            int j = wrap ? (delta - 514) : (delta + 511);
            float pos = b2f(sPos[(c + wrap) * SP_STR + (j < 0 ? 0 : j)]);
            if (delta == 513) pos = 0.f;
            float s = (acc[m][jj] + pos) * 0.03125f;
            if ((word >> ((m & 1) * 16 + g * 4 + jj)) & 1u) s = -1e20f;
            acc[m][jj] = s;
            mx = fmaxf(mx, s);
        }
    }
    // row-max: lanes sharing q are xor-16/32 apart; then cross-wave
    mx = fmaxf(mx, __shfl_xor(mx, 16, 64));
    mx = fmaxf(mx, __shfl_xor(mx, 32, 64));
    if (lane < 16) sred[0][wid][c] = mx;
    __syncthreads();   // also: all sPos reads complete before sPb overlays it
    {
        float a0 = fmaxf(fmaxf(sred[0][0][c], sred[0][1][c]), fmaxf(sred[0][2][c], sred[0][3][c]));
        float a1 = fmaxf(fmaxf(sred[0][4][c], sred[0][5][c]), fmaxf(sred[0][6][c], sred[0][7][c]));
        mx = fmaxf(a0, a1);
    }

    // ---- exp + pack P (bf16) into per-wave LDS tile sPb[wid][c][k_local]
    float ls = 0.f;
    #pragma unroll
    for (int m = 0; m < 8; ++m) {
        float p0 = __expf(acc[m][0] - mx);
        float p1 = __expf(acc[m][1] - mx);
        float p2 = __expf(acc[m][2] - mx);
        float p3 = __expf(acc[m][3] - mx);
        ls += (p0 + p1) + (p2 + p3);
        uint2 w;
        w.x = pk2(p0, p1);
        w.y = pk2(p2, p3);
        *(uint2*)&sPb[(wid * 16 + c) * PB_STR + m * 16 + g * 4] = w;
    }
    ls += __shfl_xor(ls, 16, 64);
    ls += __shfl_xor(ls, 32, 64);
    if (lane < 16) sred[1][wid][c] = ls;

    // ---- PV: prefetch ALL V loads (coalesced 1KB chunks) while ls-barrier settles
    short8 va[4][4];
    #pragma unroll
    for (int ch = 0; ch < 4; ++ch)
        #pragma unroll
        for (int dm = 0; dm < 4; ++dm)
            va[ch][dm] = *(const short8*)&vtn[((((((size_t)bh * 8 + wid) * 4 + ch) * 4 + dm) * 64) * 8) + lch];
    __syncthreads();   // sPb writes visible; all waves' P staged
    float ls2;
    {
        float a0 = (sred[1][0][c] + sred[1][1][c]) + (sred[1][2][c] + sred[1][3][c]);
        float a1 = (sred[1][4][c] + sred[1][5][c]) + (sred[1][6][c] + sred[1][7][c]);
        ls2 = a0 + a1;
    }
    if (wid == 0 && lane < 16) ssinv[c] = 1.0f / ls2;

    f32x4 oacc[4];
    #pragma unroll
    for (int dm = 0; dm < 4; ++dm) oacc[dm] = (f32x4){0.f, 0.f, 0.f, 0.f};
    short8 pbv[4];
    #pragma unroll
    for (int ch = 0; ch < 4; ++ch)
        pbv[ch] = *(const short8*)&sPb[(wid * 16 + c) * PB_STR + ch * 32 + g * 8];
    #pragma unroll
    for (int ch = 0; ch < 4; ++ch)
        #pragma unroll
        for (int dm = 0; dm < 4; ++dm)
            oacc[dm] = MFMA16(va[ch][dm], pbv[ch], oacc[dm]);

    // cross-wave O reduction (overlay sO on union region; PV sPb reads done)
    __syncthreads();
    #pragma unroll
    for (int dm = 0; dm < 4; ++dm)
        #pragma unroll
        for (int jj = 0; jj < 4; ++jj)
            sO[wid * 1088 + (dm * 16 + g * 4 + jj) * 17 + c] = oacc[dm][jj];
    __syncthreads();
    for (int e = tid; e < 1024; e += 512) {
        int d = e & 63, qq = e >> 6;
        float v = ((sO[d * 17 + qq] + sO[1088 + d * 17 + qq]) +
                   (sO[2176 + d * 17 + qq] + sO[3264 + d * 17 + qq])) +
                  ((sO[4352 + d * 17 + qq] + sO[5440 + d * 17 + qq]) +
                   (sO[6528 + d * 17 + qq] + sO[7616 + d * 17 + qq]));
        v *= ssinv[qq];
        alpha[((size_t)(q0 + qq) * 8 + b) * 1024 + h * 64 + d] = f2b(v);
    }
}

// ---------------- launcher ----------------
// Workspace: EXACTLY 88,081,408 bytes (round-3/6..10 proven footprint), r7 alias scheme.
extern "C" void kernel_launch(void* const* d_in, const int* in_sizes, int n_in,
                              void* d_out, int out_size, void* d_ws, size_t ws_size,
                              hipStream_t stream) {
    char* ws = (char*)d_ws;
    int* flags = (int*)ws;
    ushort_t* WqT   = (ushort_t*)(ws + 1024);
    ushort_t* WkT   = WqT + 1048576;
    ushort_t* WvT   = WkT + 1048576;
    ushort_t* WposT = WvT + 1048576;
    ushort_t* WoT   = WposT + 1048576;
    ushort_t* qUw   = WoT + 1048576;            // 4,194,304
    ushort_t* qVw   = qUw + 4194304;            // 4,194,304
    ushort_t* khw   = qVw + 4194304;            // 8,388,608
    ushort_t* Rlw   = khw + 8388608;            // 1,048,576
    ushort_t* R1    = Rlw + 1048576;            // 4,194,304
    ushort_t* R2    = R1 + 4194304;             // 8,388,608
    ushort_t* R3    = R2 + 8388608;             // 8,388,608
    // aliases (lifetime-disjoint, stream-ordered):
    ushort_t* qbf = R1;     // convert out -> read by qGEMM -> dead
    ushort_t* alw = R1;     // attn out -> read by outGEMM
    ushort_t* kbf = R2;     // convert out -> read by kGEMM -> dead
    ushort_t* vhw = R2;     // vGEMM out -> read by vtrans -> dead
    ushort_t* vbf = R3;     // convert out -> read by vGEMM -> dead
    ushort_t* vTw = R3;     // vtrans out -> read by attn
    uint_t* mbits = (uint_t*)WqT;  // 131,072 u32 (WqT dead after qGEMM)

    detect_kernel<<<1, 256, 0, stream>>>(d_in[6], d_in[7], flags);
    // bulk input conversion to bf16 (query, key, value)
    convert_kernel<<<2048, 256, 0, stream>>>(d_in[0], qbf, 524288, flags);
    convert_kernel<<<4096, 256, 0, stream>>>(d_in[1], kbf, 1048576, flags);
    convert_kernel<<<4096, 256, 0, stream>>>(d_in[2], vbf, 1048576, flags);
    // weight transposes
    transpose_kernel<<<dim3(32, 32, 5), dim3(32, 8), 0, stream>>>(
        d_in[8], d_in[10], d_in[12], d_in[14], d_in[15],
        WqT, WkT, WvT, WposT, WoT, flags);
    // q projection -> qU, qV fragment-native (last reader of WqT and qbf)
    gemm_kernel<0><<<dim3(32, 8), 256, 0, stream>>>(qbf, WqT, 4096, d_in[9], d_in[4], d_in[5], qUw, qVw, flags, 0);
    // mask+padding bit prepack (into dead WqT region)
    maskprep_kernel<<<512, 256, 0, stream>>>(d_in[6], d_in[7], mbits, flags);
    // k projection -> fragment-native ; v projection -> (b,h,k,d) for vtrans
    gemm_kernel<4><<<dim3(64, 8), 256, 0, stream>>>(kbf, WkT, 8192, d_in[11], nullptr, nullptr, khw, nullptr, flags, 0);
    gemm_kernel<1><<<dim3(64, 8), 256, 0, stream>>>(vbf, WvT, 8192, d_in[13], nullptr, nullptr, vhw, nullptr, flags, 0);
    // R projection -> fragment-native (raw pos_embedding, scalar-convert staging when f32)
    gemm_kernel<2><<<dim3(8, 8), 256, 0, stream>>>(d_in[3], WposT, 1024, nullptr, nullptr, nullptr, Rlw, nullptr, flags, 1);
    // V transpose to fragment-native tiles: R2 -> R3
    vtrans_kernel<<<dim3(16, 128), 256, 0, stream>>>(vhw, vTw);
    // fused attention (coalesced fragment loads)
    attn_kernel<<<dim3(32, 128), 512, 0, stream>>>(qUw, qVw, khw, vTw, Rlw, mbits, alw);
    // output projection
    gemm_kernel<3><<<dim3(32, 8), 256, 0, stream>>>(alw, WoT, 4096, d_in[16], nullptr, nullptr, d_out, nullptr, flags, 0);
}

// Round 12
// 330.280 us; speedup vs baseline: 1.3337x; 1.0521x over previous
//
#include <hip/hip_runtime.h>

#define QLEN 512
#define KLEN 1024
#define BATCH 8
#define HEADS 16
#define HDIM 64
#define EMBED 1024

typedef __attribute__((ext_vector_type(4))) float f32x4;
typedef __attribute__((ext_vector_type(8))) short short8;
typedef unsigned short ushort_t;
typedef unsigned char uchar_t;
typedef unsigned int uint_t;

#define MFMA16(a, b, c) __builtin_amdgcn_mfma_f32_16x16x32_bf16((a), (b), (c), 0, 0, 0)

__device__ __forceinline__ float b2f(ushort_t u) {
    union { uint_t i; float f; } c; c.i = ((uint_t)u) << 16; return c.f;
}
// round-half-up f32->bf16: 2 VALU ops (vs 5 for RNE); max error 0.5 ulp, ties-only diff
__device__ __forceinline__ ushort_t f2b(float x) {
    union { float f; uint_t i; } c; c.f = x;
    return (ushort_t)((c.i + 0x8000u) >> 16);
}
__device__ __forceinline__ uint_t pk2(float lo, float hi) {
    return (uint_t)f2b(lo) | ((uint_t)f2b(hi) << 16);
}
// load a "float" that may be stored as f32 or bf16
__device__ __forceinline__ float ldf(const void* p, int idx, int f32m) {
    if (f32m) return ((const float*)p)[idx];
    return b2f(((const ushort_t*)p)[idx]);
}

typedef const __attribute__((address_space(1))) void async_src_t;
typedef __attribute__((address_space(3))) void async_dst_t;

// ---------------- dtype detector ----------------
// flags[0]: 1 if float tensors are f32, 0 if bf16
// flags[1]: mask mode: 0=int32, 1=uint8, 2=bf16, 3=f32
__global__ __launch_bounds__(256) void detect_kernel(const void* mask, const void* pad, int* flags) {
    __shared__ int cnt[4];
    int tid = threadIdx.x;
    if (tid < 4) cnt[tid] = 0;
    __syncthreads();
    const uchar_t* mb = (const uchar_t*)mask;
    const uchar_t* pb = (const uchar_t*)pad;
    int lnz1 = 0, l3f1 = 0, l3f3 = 0, lpnz = 0;
    for (int off = tid; off < 4096; off += 256) {
        uchar_t v = mb[off];
        int m4 = off & 3;
        if (m4 != 0 && v != 0) lnz1++;
        if (m4 == 1 && v == 0x3F) l3f1++;
        if (m4 == 3 && v == 0x3F) l3f3++;
        uchar_t p = pb[off];
        if (m4 == 0 && p != 0) lpnz++;
    }
    atomicAdd(&cnt[0], lnz1); atomicAdd(&cnt[1], l3f1);
    atomicAdd(&cnt[2], l3f3); atomicAdd(&cnt[3], lpnz);
    __syncthreads();
    if (tid == 0) {
        flags[0] = (cnt[3] == 0) ? 1 : 0;
        int mm;
        if (cnt[0] == 0) mm = 0;
        else if (cnt[1] > 16) mm = 2;
        else if (cnt[2] > 16) mm = 3;
        else mm = 1;
        flags[1] = mm;
    }
}

// ---------------- bulk convert to bf16 ----------------
__global__ __launch_bounds__(256) void convert_kernel(const void* __restrict__ src,
                                                      ushort_t* __restrict__ dst,
                                                      int n8, const int* flags) {
    int i = blockIdx.x * 256 + threadIdx.x;
    if (i >= n8) return;
    if (flags[0]) {
        const float4* s = (const float4*)src + (size_t)i * 2;
        float4 a = s[0], b = s[1];
        uint4 o;
        o.x = pk2(a.x, a.y); o.y = pk2(a.z, a.w);
        o.z = pk2(b.x, b.y); o.w = pk2(b.z, b.w);
        ((uint4*)dst)[i] = o;
    } else {
        ((uint4*)dst)[i] = ((const uint4*)src)[i];
    }
}

// ---------------- mask+padding prepack: dead-bit per (b,q,k), layout [b][w4][q][w&3] ----------------
__global__ __launch_bounds__(256) void maskprep_kernel(const void* __restrict__ mask,
                                                       const void* __restrict__ pad,
                                                       uint_t* __restrict__ bits,
                                                       const int* flags) {
    int tid = blockIdx.x * 256 + threadIdx.x;   // 8*512*32 = 131072 threads
    int w = tid & 31, q = (tid >> 5) & 511, b = tid >> 14;
    int mm = flags[1], f32m = flags[0];
    float padq = ldf(pad, b * 512 + q, f32m);
    uint_t word = 0;
    for (int j = 0; j < 32; ++j) {
        int k = w * 32 + j;
        size_t mi = (size_t)q * 1024 + k;
        int dead;
        if (mm == 1) dead = (((const uchar_t*)mask)[mi] != 0);
        else if (mm == 2) dead = (((const ushort_t*)mask)[mi] != 0);
        else dead = (((const uint_t*)mask)[mi] != 0);
        if (k >= 512) {
            float padk = ldf(pad, b * 512 + k - 512, f32m);
            if (padq == 0.f || padk == 0.f) dead = 1;
        }
        word |= ((uint_t)dead) << j;
    }
    // transposed layout: [b][w>>2][q][w&3] so attn's uint4 read is q-contiguous
    bits[((b * 8 + (w >> 2)) * 512 + q) * 4 + (w & 3)] = word;
}

// ---------------- weight transpose (to bf16 W^T) ----------------
__global__ __launch_bounds__(256) void transpose_kernel(
    const void* W0, const void* W1, const void* W2, const void* W3, const void* W4,
    ushort_t* T0, ushort_t* T1, ushort_t* T2, ushort_t* T3, ushort_t* T4,
    const int* flags) {
    __shared__ float tl[32][33];
    int f32m = flags[0];
    const void* W; ushort_t* T;
    switch (blockIdx.z) {
        case 0: W = W0; T = T0; break;
        case 1: W = W1; T = T1; break;
        case 2: W = W2; T = T2; break;
        case 3: W = W3; T = T3; break;
        default: W = W4; T = T4; break;
    }
    int tx = threadIdx.x, ty = threadIdx.y;  // (32,8)
    int x = blockIdx.x * 32 + tx;
    #pragma unroll
    for (int j = 0; j < 4; ++j) {
        int row = blockIdx.y * 32 + ty + j * 8;
        tl[ty + j * 8][tx] = ldf(W, row * 1024 + x, f32m);
    }
    __syncthreads();
    #pragma unroll
    for (int j = 0; j < 4; ++j) {
        int n = blockIdx.x * 32 + ty + j * 8;
        T[n * 1024 + blockIdx.y * 32 + tx] = f2b(tl[tx][ty + j * 8]);
    }
}

// ---------------- V transpose to fragment-native tiles ----------------
// in : vh[bh][k][d]   (b,h,k,d) from v-GEMM
// out: chunk16B idx = (((bh*8 + kc)*4 + ch)*4 + dm)*64 + c*4 + g ; elements = k-octet
//      where k = kc*128 + ch*32 + g*8 + e, d = dm*16 + c
__global__ __launch_bounds__(256) void vtrans_kernel(const ushort_t* __restrict__ vh,
                                                     ushort_t* __restrict__ vT) {
    __shared__ ushort_t t[64][68];
    int bh = blockIdx.y;
    int k0 = blockIdx.x * 64;
    int tid = threadIdx.x;
    int r = tid >> 2, c0 = (tid & 3) * 16;
    const short8* src = (const short8*)&vh[((size_t)bh * 1024 + k0 + r) * 64 + c0];
    *(short8*)&t[r][c0] = src[0];
    *(short8*)&t[r][c0 + 8] = src[1];
    __syncthreads();
    ushort_t tmp[16];
    #pragma unroll
    for (int j = 0; j < 16; ++j) tmp[j] = t[c0 + j][r];
    int dm = r >> 4, cc = r & 15;
    #pragma unroll
    for (int tt = 0; tt < 2; ++tt) {
        int og = ((k0 + c0) >> 3) + tt;
        int kc = og >> 4, ch = (og >> 2) & 3, g = og & 3;
        size_t addr = ((((((size_t)bh * 8 + kc) * 4 + ch) * 4 + dm) * 64) + cc * 4 + g) * 8;
        *(short8*)&vT[addr] = *(short8*)&tmp[tt * 8];
    }
}

// ---------------- projection GEMM (global_load_lds, linear LDS) ----------------
// EPI 0: qU/qV, fragment-native, PRE-SCALED by 1/32 (fold of softmax scale)
// EPI 1: v proj, old (b,h,k,d) layout (vtrans input)
// EPI 2: R proj, fragment-native
// EPI 3: out proj (adds bias, writes d_out (q,b,e), dtype per flag)
// EPI 4: k proj, fragment-native
template<int EPI>
__global__ __launch_bounds__(256) void gemm_kernel(
    const void* Av, const ushort_t* BT, int M,
    const void* bias, const void* Up, const void* Vp,
    void* out0, void* out1, const int* flags, int a_mode) {
    __shared__ ushort_t As[4096];
    __shared__ ushort_t Bs[4096];
    const int f32m = flags[0];
    const int a_f32 = a_mode ? f32m : 0;
    const int tid = threadIdx.x;
    const int wid = tid >> 6, lane = tid & 63;
    const int wr = (wid >> 1) * 64, wc = (wid & 1) * 64;
    const int m0 = blockIdx.x * 128, n0 = blockIdx.y * 128;
    const int ch0 = wid * 2;
    const int lrow = lane >> 2, lcol = (lane & 3) * 8;

    f32x4 acc[4][4];
    #pragma unroll
    for (int m = 0; m < 4; ++m)
        #pragma unroll
        for (int n = 0; n < 4; ++n)
            acc[m][n] = (f32x4){0.f, 0.f, 0.f, 0.f};

    for (int k0 = 0; k0 < 1024; k0 += 32) {
        if (a_f32) {
            const float* Af = (const float*)Av + (size_t)(m0 + (tid >> 1)) * 1024 + k0 + (tid & 1) * 16;
            ushort_t* dst = &As[(tid >> 1) * 32 + (tid & 1) * 16];
            #pragma unroll
            for (int e = 0; e < 16; ++e) dst[e] = f2b(Af[e]);
        } else {
            #pragma unroll
            for (int t = 0; t < 2; ++t) {
                int ch = ch0 + t;
                const ushort_t* ga = (const ushort_t*)Av + (size_t)(m0 + ch * 16 + lrow) * 1024 + k0 + lcol;
                __builtin_amdgcn_global_load_lds((async_src_t*)ga, (async_dst_t*)&As[ch * 512], 16, 0, 0);
            }
        }
        #pragma unroll
        for (int t = 0; t < 2; ++t) {
            int ch = ch0 + t;
            const ushort_t* gb = BT + (size_t)(n0 + ch * 16 + lrow) * 1024 + k0 + lcol;
            __builtin_amdgcn_global_load_lds((async_src_t*)gb, (async_dst_t*)&Bs[ch * 512], 16, 0, 0);
        }
        __syncthreads();

        short8 af[4], bf[4];
        #pragma unroll
        for (int m = 0; m < 4; ++m)
            af[m] = *(const short8*)&As[(wr + m * 16 + (lane & 15)) * 32 + (lane >> 4) * 8];
        #pragma unroll
        for (int n = 0; n < 4; ++n)
            bf[n] = *(const short8*)&Bs[(wc + n * 16 + (lane & 15)) * 32 + (lane >> 4) * 8];
        #pragma unroll
        for (int m = 0; m < 4; ++m)
            #pragma unroll
            for (int n = 0; n < 4; ++n)
                acc[m][n] = MFMA16(af[m], bf[n], acc[m][n]);
        __syncthreads();
    }

    #pragma unroll
    for (int n = 0; n < 4; ++n) {
        int gn = n0 + wc + n * 16 + (lane & 15);
        float bv_ = (EPI == 2) ? 0.f : ldf(bias, gn, f32m);
        float uu = 0.f, vv = 0.f;
        if (EPI == 0) { uu = ldf(Up, gn, f32m); vv = ldf(Vp, gn, f32m); }
        #pragma unroll
        for (int m = 0; m < 4; ++m) {
            #pragma unroll
            for (int j = 0; j < 4; ++j) {
                int gm = m0 + wr + m * 16 + (lane >> 4) * 4 + j;
                float c = acc[m][n][j] + bv_;
                if (EPI == 0) {
                    int q = gm >> 3, b = gm & 7;
                    int h = gn >> 6, d = gn & 63;
                    int bhk = b * 16 + h;
                    size_t addr = ((size_t)bhk * 32 + (q >> 4)) * 1024 + (size_t)(d >> 5) * 512
                                  + ((q & 15) * 4 + ((d >> 3) & 3)) * 8 + (d & 7);
                    // pre-scale by 1/32: folds the softmax 1/sqrt(E) into the projection
                    ((ushort_t*)out0)[addr] = f2b((c + uu) * 0.03125f);
                    ((ushort_t*)out1)[addr] = f2b((c + vv) * 0.03125f);
                } else if (EPI == 1) {
                    int kk = gm >> 3, b = gm & 7;
                    int h = gn >> 6, d = gn & 63;
                    ((ushort_t*)out0)[((b * 16 + h) * 1024 + kk) * 64 + d] = f2b(c);
                } else if (EPI == 2) {
                    int h = gn >> 6, d = gn & 63;
                    int jr = gm;
                    size_t addr = (((((size_t)h * 8 + (jr >> 7)) * 8 + ((jr >> 4) & 7)) * 2 + (d >> 5)) * 64
                                   + ((jr & 15) * 4 + ((d >> 3) & 3))) * 8 + (d & 7);
                    ((ushort_t*)out0)[addr] = f2b(c);
                } else if (EPI == 4) {
                    int kk = gm >> 3, b = gm & 7;
                    int h = gn >> 6, d = gn & 63;
                    size_t addr = ((((((size_t)(b * 16 + h)) * 8 + (kk >> 7)) * 8 + ((kk >> 4) & 7)) * 2 + (d >> 5)) * 64
                                   + ((kk & 15) * 4 + ((d >> 3) & 3))) * 8 + (d & 7);
                    ((ushort_t*)out0)[addr] = f2b(c);
                } else {
                    if (f32m) ((float*)out0)[gm * 1024 + gn] = c;
                    else ((ushort_t*)out0)[gm * 1024 + gn] = f2b(c);
                }
            }
        }
    }
}

// ---------------- fused attention (fragment-native coalesced loads, 8 waves) ----------------
// block: 16 q-rows x one (b,h); 8 waves, wave w owns k in [w*128, w*128+128)
// Lane: c = lane&15 = q-column, g = lane>>4. S^T C-layout: col=c(q), row=k-local.
// qU/qV arrive pre-scaled by 1/32, so score = content + position directly.
#define SP_STR 1032   // sPos row stride (ushorts): 516 words % 32 = 4 -> 2-way banks (free)
#define PB_STR 136    // sPb row stride (ushorts): 68 words % 32 = 4 -> 2-way banks (free)
__global__ __launch_bounds__(512, 4) void attn_kernel(
    const ushort_t* __restrict__ qU, const ushort_t* __restrict__ qV,
    const ushort_t* __restrict__ khn, const ushort_t* __restrict__ vtn,
    const ushort_t* __restrict__ Rln, const uint_t* __restrict__ mbits,
    ushort_t* __restrict__ alpha) {

    // union region: sPos [17][1032] u16 (35,088 B) | sPb [8][16][136] u16 (34,816 B)
    //             | sO [8][1088] f32 (34,816 B). Aliasing is barrier-separated.
    __shared__ __align__(16) uchar_t uni[35104];
    ushort_t* sPos = (ushort_t*)uni;
    ushort_t* sPb  = (ushort_t*)uni;
    float*    sO   = (float*)uni;
    __shared__ float sred[2][8][16];
    __shared__ float ssinv[16];

    const int tid = threadIdx.x;
    const int wid = tid >> 6, lane = tid & 63;
    const int g = lane >> 4, c = lane & 15;
    const int qt = blockIdx.x;
    const int q0 = qt * 16;
    const int bh = blockIdx.y;
    const int b = bh >> 4, h = bh & 15;
    const int kbase = wid * 128;
    const int lch = (c * 4 + g) * 8;   // ushort offset of this lane's 16B chunk

    // ---- position: PR^T[j][q] = R[j] . qV[q];  write PR[q][j] (bf16) to sPos
    {
        size_t qvb = ((size_t)bh * 32 + qt) * 1024;
        short8 bva0 = *(const short8*)&qV[qvb + lch];
        short8 bva1 = *(const short8*)&qV[qvb + 512 + lch];
        int qtb = (qt == 31) ? 31 : qt + 1;
        int cb = (qt == 31) ? 15 : c;
        size_t qvb2 = ((size_t)bh * 32 + qtb) * 1024;
        short8 bvb0 = *(const short8*)&qV[qvb2 + (cb * 4 + g) * 8];
        short8 bvb1 = *(const short8*)&qV[qvb2 + 512 + (cb * 4 + g) * 8];
        #pragma unroll
        for (int m = 0; m < 8; ++m) {
            size_t rb = ((((size_t)h * 8 + wid) * 8 + m) * 2) * 512;
            short8 ra0 = *(const short8*)&Rln[rb + lch];
            short8 ra1 = *(const short8*)&Rln[rb + 512 + lch];
            f32x4 p0 = (f32x4){0.f, 0.f, 0.f, 0.f};
            p0 = MFMA16(ra0, bva0, p0);
            p0 = MFMA16(ra1, bva1, p0);
            f32x4 p1 = (f32x4){0.f, 0.f, 0.f, 0.f};
            p1 = MFMA16(ra0, bvb0, p1);
            p1 = MFMA16(ra1, bvb1, p1);
            uint2 w;
            w.x = pk2(p0[0], p0[1]);
            w.y = pk2(p0[2], p0[3]);
            *(uint2*)&sPos[c * SP_STR + kbase + m * 16 + g * 4] = w;
            if (c == 0) {
                uint2 x;
                x.x = pk2(p1[0], p1[1]);
                x.y = pk2(p1[2], p1[3]);
                *(uint2*)&sPos[16 * SP_STR + kbase + m * 16 + g * 4] = x;
            }
        }
    }

    // ---- content: S^T[k][q] = K[k] . qU[q]
    f32x4 acc[8];
    {
        size_t qub = ((size_t)bh * 32 + qt) * 1024;
        short8 bu0 = *(const short8*)&qU[qub + lch];
        short8 bu1 = *(const short8*)&qU[qub + 512 + lch];
        #pragma unroll
        for (int m = 0; m < 8; ++m) {
            size_t kb = ((((size_t)bh * 8 + wid) * 8 + m) * 2) * 512;
            short8 ka0 = *(const short8*)&khn[kb + lch];
            short8 ka1 = *(const short8*)&khn[kb + 512 + lch];
            f32x4 t = (f32x4){0.f, 0.f, 0.f, 0.f};
            t = MFMA16(ka0, bu0, t);
            t = MFMA16(ka1, bu1, t);
            acc[m] = t;
        }
    }
    __syncthreads();

    // ---- mask bits: one coalesced uint4 per thread (128 k-bits = this wave's range)
    const int q = q0 + c;
    uint4 mw = *(const uint4*)(mbits + ((size_t)(b * 8 + wid) * 512 + q) * 4);
    uint_t mwa[4] = {mw.x, mw.y, mw.z, mw.w};

    // ---- score: add rel-shifted position (sPos gather), mask bits (already scaled)
    float mx = -3.0e38f;
    #pragma unroll
    for (int m = 0; m < 8; ++m) {
        int k0e = kbase + m * 16 + g * 4;
        uint_t word = mwa[m >> 1];
        #pragma unroll
        for (int jj = 0; jj < 4; ++jj) {
            int k = k0e + jj;
            int delta = k - q;
            int wrap = (delta > 512) ? 1 : 0;
            int j = wrap ? (delta - 514) : (delta + 511);
            float pos = b2f(sPos[(c + wrap) * SP_STR + (j < 0 ? 0 : j)]);
            if (delta == 513) pos = 0.f;
            float s = acc[m][jj] + pos;
            if ((word >> ((m & 1) * 16 + g * 4 + jj)) & 1u) s = -1e20f;
            acc[m][jj] = s;
            mx = fmaxf(mx, s);
        }
    }
    // row-max: lanes sharing q are xor-16/32 apart; then cross-wave
    mx = fmaxf(mx, __shfl_xor(mx, 16, 64));
    mx = fmaxf(mx, __shfl_xor(mx, 32, 64));
    if (lane < 16) sred[0][wid][c] = mx;
    __syncthreads();   // also: all sPos reads complete before sPb overlays it
    {
        float a0 = fmaxf(fmaxf(sred[0][0][c], sred[0][1][c]), fmaxf(sred[0][2][c], sred[0][3][c]));
        float a1 = fmaxf(fmaxf(sred[0][4][c], sred[0][5][c]), fmaxf(sred[0][6][c], sred[0][7][c]));
        mx = fmaxf(a0, a1);
    }

    // ---- exp + pack P (bf16) into per-wave LDS tile sPb[wid][c][k_local]
    float ls = 0.f;
    #pragma unroll
    for (int m = 0; m < 8; ++m) {
        float p0 = __expf(acc[m][0] - mx);
        float p1 = __expf(acc[m][1] - mx);
        float p2 = __expf(acc[m][2] - mx);
        float p3 = __expf(acc[m][3] - mx);
        ls += (p0 + p1) + (p2 + p3);
        uint2 w;
        w.x = pk2(p0, p1);
        w.y = pk2(p2, p3);
        *(uint2*)&sPb[(wid * 16 + c) * PB_STR + m * 16 + g * 4] = w;
    }
    ls += __shfl_xor(ls, 16, 64);
    ls += __shfl_xor(ls, 32, 64);
    if (lane < 16) sred[1][wid][c] = ls;

    // ---- PV: prefetch ALL V loads (coalesced 1KB chunks) while ls-barrier settles
    short8 va[4][4];
    #pragma unroll
    for (int ch = 0; ch < 4; ++ch)
        #pragma unroll
        for (int dm = 0; dm < 4; ++dm)
            va[ch][dm] = *(const short8*)&vtn[((((((size_t)bh * 8 + wid) * 4 + ch) * 4 + dm) * 64) * 8) + lch];
    __syncthreads();   // sPb writes visible; all waves' P staged
    float ls2;
    {
        float a0 = (sred[1][0][c] + sred[1][1][c]) + (sred[1][2][c] + sred[1][3][c]);
        float a1 = (sred[1][4][c] + sred[1][5][c]) + (sred[1][6][c] + sred[1][7][c]);
        ls2 = a0 + a1;
    }
    if (wid == 0 && lane < 16) ssinv[c] = 1.0f / ls2;

    f32x4 oacc[4];
    #pragma unroll
    for (int dm = 0; dm < 4; ++dm) oacc[dm] = (f32x4){0.f, 0.f, 0.f, 0.f};
    short8 pbv[4];
    #pragma unroll
    for (int ch = 0; ch < 4; ++ch)
        pbv[ch] = *(const short8*)&sPb[(wid * 16 + c) * PB_STR + ch * 32 + g * 8];
    #pragma unroll
    for (int ch = 0; ch < 4; ++ch)
        #pragma unroll
        for (int dm = 0; dm < 4; ++dm)
            oacc[dm] = MFMA16(va[ch][dm], pbv[ch], oacc[dm]);

    // cross-wave O reduction (overlay sO on union region; PV sPb reads done)
    __syncthreads();
    #pragma unroll
    for (int dm = 0; dm < 4; ++dm)
        #pragma unroll
        for (int jj = 0; jj < 4; ++jj)
            sO[wid * 1088 + (dm * 16 + g * 4 + jj) * 17 + c] = oacc[dm][jj];
    __syncthreads();
    for (int e = tid; e < 1024; e += 512) {
        int d = e & 63, qq = e >> 6;
        float v = ((sO[d * 17 + qq] + sO[1088 + d * 17 + qq]) +
                   (sO[2176 + d * 17 + qq] + sO[3264 + d * 17 + qq])) +
                  ((sO[4352 + d * 17 + qq] + sO[5440 + d * 17 + qq]) +
                   (sO[6528 + d * 17 + qq] + sO[7616 + d * 17 + qq]));
        v *= ssinv[qq];
        alpha[((size_t)(q0 + qq) * 8 + b) * 1024 + h * 64 + d] = f2b(v);
    }
}

// ---------------- launcher ----------------
// Workspace: EXACTLY 88,081,408 bytes (round-3/6..11 proven footprint), r7 alias scheme.
extern "C" void kernel_launch(void* const* d_in, const int* in_sizes, int n_in,
                              void* d_out, int out_size, void* d_ws, size_t ws_size,
                              hipStream_t stream) {
    char* ws = (char*)d_ws;
    int* flags = (int*)ws;
    ushort_t* WqT   = (ushort_t*)(ws + 1024);
    ushort_t* WkT   = WqT + 1048576;
    ushort_t* WvT   = WkT + 1048576;
    ushort_t* WposT = WvT + 1048576;
    ushort_t* WoT   = WposT + 1048576;
    ushort_t* qUw   = WoT + 1048576;            // 4,194,304
    ushort_t* qVw   = qUw + 4194304;            // 4,194,304
    ushort_t* khw   = qVw + 4194304;            // 8,388,608
    ushort_t* Rlw   = khw + 8388608;            // 1,048,576
    ushort_t* R1    = Rlw + 1048576;            // 4,194,304
    ushort_t* R2    = R1 + 4194304;             // 8,388,608
    ushort_t* R3    = R2 + 8388608;             // 8,388,608
    // aliases (lifetime-disjoint, stream-ordered):
    ushort_t* qbf = R1;     // convert out -> read by qGEMM -> dead
    ushort_t* alw = R1;     // attn out -> read by outGEMM
    ushort_t* kbf = R2;     // convert out -> read by kGEMM -> dead
    ushort_t* vhw = R2;     // vGEMM out -> read by vtrans -> dead
    ushort_t* vbf = R3;     // convert out -> read by vGEMM -> dead
    ushort_t* vTw = R3;     // vtrans out -> read by attn
    uint_t* mbits = (uint_t*)WqT;  // 131,072 u32 (WqT dead after qGEMM)
    ushort_t* pbf = WvT;    // pos bf16 (WvT dead after vGEMM)

    detect_kernel<<<1, 256, 0, stream>>>(d_in[6], d_in[7], flags);
    // bulk input conversion to bf16 (query, key, value)
    convert_kernel<<<2048, 256, 0, stream>>>(d_in[0], qbf, 524288, flags);
    convert_kernel<<<4096, 256, 0, stream>>>(d_in[1], kbf, 1048576, flags);
    convert_kernel<<<4096, 256, 0, stream>>>(d_in[2], vbf, 1048576, flags);
    // weight transposes
    transpose_kernel<<<dim3(32, 32, 5), dim3(32, 8), 0, stream>>>(
        d_in[8], d_in[10], d_in[12], d_in[14], d_in[15],
        WqT, WkT, WvT, WposT, WoT, flags);
    // q projection -> qU, qV fragment-native, pre-scaled (last reader of WqT and qbf)
    gemm_kernel<0><<<dim3(32, 8), 256, 0, stream>>>(qbf, WqT, 4096, d_in[9], d_in[4], d_in[5], qUw, qVw, flags, 0);
    // mask+padding bit prepack (into dead WqT region)
    maskprep_kernel<<<512, 256, 0, stream>>>(d_in[6], d_in[7], mbits, flags);
    // k projection -> fragment-native ; v projection -> (b,h,k,d) for vtrans
    gemm_kernel<4><<<dim3(64, 8), 256, 0, stream>>>(kbf, WkT, 8192, d_in[11], nullptr, nullptr, khw, nullptr, flags, 0);
    gemm_kernel<1><<<dim3(64, 8), 256, 0, stream>>>(vbf, WvT, 8192, d_in[13], nullptr, nullptr, vhw, nullptr, flags, 0);
    // pos_embedding -> bf16 (into dead WvT region), then R projection (fast A path)
    convert_kernel<<<512, 256, 0, stream>>>(d_in[3], pbf, 131072, flags);
    gemm_kernel<2><<<dim3(8, 8), 256, 0, stream>>>(pbf, WposT, 1024, nullptr, nullptr, nullptr, Rlw, nullptr, flags, 0);
    // V transpose to fragment-native tiles: R2 -> R3
    vtrans_kernel<<<dim3(16, 128), 256, 0, stream>>>(vhw, vTw);
    // fused attention (coalesced fragment loads)
    attn_kernel<<<dim3(32, 128), 512, 0, stream>>>(qUw, qVw, khw, vTw, Rlw, mbits, alw);
    // output projection
    gemm_kernel<3><<<dim3(32, 8), 256, 0, stream>>>(alw, WoT, 4096, d_in[16], nullptr, nullptr, d_out, nullptr, flags, 0);
}

// Round 13
// 316.091 us; speedup vs baseline: 1.3936x; 1.0449x over previous
//
#include <hip/hip_runtime.h>

#define QLEN 512
#define KLEN 1024
#define BATCH 8
#define HEADS 16
#define HDIM 64
#define EMBED 1024

typedef __attribute__((ext_vector_type(4))) float f32x4;
typedef __attribute__((ext_vector_type(8))) short short8;
typedef unsigned short ushort_t;
typedef unsigned char uchar_t;
typedef unsigned int uint_t;

#define MFMA16(a, b, c) __builtin_amdgcn_mfma_f32_16x16x32_bf16((a), (b), (c), 0, 0, 0)

__device__ __forceinline__ float b2f(ushort_t u) {
    union { uint_t i; float f; } c; c.i = ((uint_t)u) << 16; return c.f;
}
// round-half-up f32->bf16: 2 VALU ops; max error 0.5 ulp
__device__ __forceinline__ ushort_t f2b(float x) {
    union { float f; uint_t i; } c; c.f = x;
    return (ushort_t)((c.i + 0x8000u) >> 16);
}
__device__ __forceinline__ uint_t pk2(float lo, float hi) {
    return (uint_t)f2b(lo) | ((uint_t)f2b(hi) << 16);
}
__device__ __forceinline__ float ldf(const void* p, int idx, int f32m) {
    if (f32m) return ((const float*)p)[idx];
    return b2f(((const ushort_t*)p)[idx]);
}

typedef const __attribute__((address_space(1))) void async_src_t;
typedef __attribute__((address_space(3))) void async_dst_t;

// ---------------- dtype detector ----------------
__global__ __launch_bounds__(256) void detect_kernel(const void* mask, const void* pad, int* flags) {
    __shared__ int cnt[4];
    int tid = threadIdx.x;
    if (tid < 4) cnt[tid] = 0;
    __syncthreads();
    const uchar_t* mb = (const uchar_t*)mask;
    const uchar_t* pb = (const uchar_t*)pad;
    int lnz1 = 0, l3f1 = 0, l3f3 = 0, lpnz = 0;
    for (int off = tid; off < 4096; off += 256) {
        uchar_t v = mb[off];
        int m4 = off & 3;
        if (m4 != 0 && v != 0) lnz1++;
        if (m4 == 1 && v == 0x3F) l3f1++;
        if (m4 == 3 && v == 0x3F) l3f3++;
        uchar_t p = pb[off];
        if (m4 == 0 && p != 0) lpnz++;
    }
    atomicAdd(&cnt[0], lnz1); atomicAdd(&cnt[1], l3f1);
    atomicAdd(&cnt[2], l3f3); atomicAdd(&cnt[3], lpnz);
    __syncthreads();
    if (tid == 0) {
        flags[0] = (cnt[3] == 0) ? 1 : 0;
        int mm;
        if (cnt[0] == 0) mm = 0;
        else if (cnt[1] > 16) mm = 2;
        else if (cnt[2] > 16) mm = 3;
        else mm = 1;
        flags[1] = mm;
    }
}

// ---------------- merged prep: converts (q,k,v) + 5 weight transposes ----------------
__device__ __forceinline__ void conv_body(const void* __restrict__ src, ushort_t* __restrict__ dst,
                                          int i, int n8, int f32m) {
    if (i >= n8) return;
    if (f32m) {
        const float4* s = (const float4*)src + (size_t)i * 2;
        float4 a = s[0], b = s[1];
        uint4 o;
        o.x = pk2(a.x, a.y); o.y = pk2(a.z, a.w);
        o.z = pk2(b.x, b.y); o.w = pk2(b.z, b.w);
        ((uint4*)dst)[i] = o;
    } else {
        ((uint4*)dst)[i] = ((const uint4*)src)[i];
    }
}

__global__ __launch_bounds__(256) void prep_kernel(
    const void* q_in, ushort_t* qbf, const void* k_in, ushort_t* kbf,
    const void* v_in, ushort_t* vbf,
    const void* W0, const void* W1, const void* W2, const void* W3, const void* W4,
    ushort_t* T0, ushort_t* T1, ushort_t* T2, ushort_t* T3, ushort_t* T4,
    const int* flags) {
    __shared__ float tl[32][33];
    const int bid = blockIdx.x;
    const int tid = threadIdx.x;
    const int f32m = flags[0];
    if (bid < 2048) {
        conv_body(q_in, qbf, bid * 256 + tid, 524288, f32m);
    } else if (bid < 6144) {
        conv_body(k_in, kbf, (bid - 2048) * 256 + tid, 1048576, f32m);
    } else if (bid < 10240) {
        conv_body(v_in, vbf, (bid - 6144) * 256 + tid, 1048576, f32m);
    } else {
        int l = bid - 10240;           // 0..5119
        int z = l >> 10, r = l & 1023;
        int bx = r & 31, by = r >> 5;
        const void* W; ushort_t* T;
        switch (z) {
            case 0: W = W0; T = T0; break;
            case 1: W = W1; T = T1; break;
            case 2: W = W2; T = T2; break;
            case 3: W = W3; T = T3; break;
            default: W = W4; T = T4; break;
        }
        int tx = tid & 31, ty = tid >> 5;   // (32,8)
        int x = bx * 32 + tx;
        #pragma unroll
        for (int j = 0; j < 4; ++j) {
            int row = by * 32 + ty + j * 8;
            tl[ty + j * 8][tx] = ldf(W, row * 1024 + x, f32m);
        }
        __syncthreads();
        #pragma unroll
        for (int j = 0; j < 4; ++j) {
            int n = bx * 32 + ty + j * 8;
            T[n * 1024 + by * 32 + tx] = f2b(tl[tx][ty + j * 8]);
        }
    }
}

// ---------------- GEMM body (global_load_lds, linear LDS) ----------------
// EPI 0: qU/qV fragment-native, pre-scaled by 1/32
// EPI 1: v proj, (b,h,k,d) layout (vtrans input)
// EPI 2: R proj, fragment-native (a_mode=1: scalar f32 staging)
// EPI 3: out proj (writes d_out (q,b,e))
// EPI 4: k proj, fragment-native
template<int EPI>
__device__ __forceinline__ void gemm_body(
    int mt, int nt, const void* Av, const ushort_t* BT,
    const void* bias, const void* Up, const void* Vp,
    void* out0, void* out1, const int* flags, int a_mode,
    ushort_t* As, ushort_t* Bs) {
    const int f32m = flags[0];
    const int a_f32 = a_mode ? f32m : 0;
    const int tid = threadIdx.x;
    const int wid = tid >> 6, lane = tid & 63;
    const int wr = (wid >> 1) * 64, wc = (wid & 1) * 64;
    const int m0 = mt * 128, n0 = nt * 128;
    const int ch0 = wid * 2;
    const int lrow = lane >> 2, lcol = (lane & 3) * 8;

    f32x4 acc[4][4];
    #pragma unroll
    for (int m = 0; m < 4; ++m)
        #pragma unroll
        for (int n = 0; n < 4; ++n)
            acc[m][n] = (f32x4){0.f, 0.f, 0.f, 0.f};

    for (int k0 = 0; k0 < 1024; k0 += 32) {
        if (a_f32) {
            const float* Af = (const float*)Av + (size_t)(m0 + (tid >> 1)) * 1024 + k0 + (tid & 1) * 16;
            ushort_t* dst = &As[(tid >> 1) * 32 + (tid & 1) * 16];
            #pragma unroll
            for (int e = 0; e < 16; ++e) dst[e] = f2b(Af[e]);
        } else {
            #pragma unroll
            for (int t = 0; t < 2; ++t) {
                int ch = ch0 + t;
                const ushort_t* ga = (const ushort_t*)Av + (size_t)(m0 + ch * 16 + lrow) * 1024 + k0 + lcol;
                __builtin_amdgcn_global_load_lds((async_src_t*)ga, (async_dst_t*)&As[ch * 512], 16, 0, 0);
            }
        }
        #pragma unroll
        for (int t = 0; t < 2; ++t) {
            int ch = ch0 + t;
            const ushort_t* gb = BT + (size_t)(n0 + ch * 16 + lrow) * 1024 + k0 + lcol;
            __builtin_amdgcn_global_load_lds((async_src_t*)gb, (async_dst_t*)&Bs[ch * 512], 16, 0, 0);
        }
        __syncthreads();

        short8 af[4], bf[4];
        #pragma unroll
        for (int m = 0; m < 4; ++m)
            af[m] = *(const short8*)&As[(wr + m * 16 + (lane & 15)) * 32 + (lane >> 4) * 8];
        #pragma unroll
        for (int n = 0; n < 4; ++n)
            bf[n] = *(const short8*)&Bs[(wc + n * 16 + (lane & 15)) * 32 + (lane >> 4) * 8];
        #pragma unroll
        for (int m = 0; m < 4; ++m)
            #pragma unroll
            for (int n = 0; n < 4; ++n)
                acc[m][n] = MFMA16(af[m], bf[n], acc[m][n]);
        __syncthreads();
    }

    #pragma unroll
    for (int n = 0; n < 4; ++n) {
        int gn = n0 + wc + n * 16 + (lane & 15);
        float bv_ = (EPI == 2) ? 0.f : ldf(bias, gn, f32m);
        float uu = 0.f, vv = 0.f;
        if (EPI == 0) { uu = ldf(Up, gn, f32m); vv = ldf(Vp, gn, f32m); }
        #pragma unroll
        for (int m = 0; m < 4; ++m) {
            #pragma unroll
            for (int j = 0; j < 4; ++j) {
                int gm = m0 + wr + m * 16 + (lane >> 4) * 4 + j;
                float c = acc[m][n][j] + bv_;
                if (EPI == 0) {
                    int q = gm >> 3, b = gm & 7;
                    int h = gn >> 6, d = gn & 63;
                    int bhk = b * 16 + h;
                    size_t addr = ((size_t)bhk * 32 + (q >> 4)) * 1024 + (size_t)(d >> 5) * 512
                                  + ((q & 15) * 4 + ((d >> 3) & 3)) * 8 + (d & 7);
                    ((ushort_t*)out0)[addr] = f2b((c + uu) * 0.03125f);
                    ((ushort_t*)out1)[addr] = f2b((c + vv) * 0.03125f);
                } else if (EPI == 1) {
                    int kk = gm >> 3, b = gm & 7;
                    int h = gn >> 6, d = gn & 63;
                    ((ushort_t*)out0)[((b * 16 + h) * 1024 + kk) * 64 + d] = f2b(c);
                } else if (EPI == 2) {
                    int h = gn >> 6, d = gn & 63;
                    int jr = gm;
                    size_t addr = (((((size_t)h * 8 + (jr >> 7)) * 8 + ((jr >> 4) & 7)) * 2 + (d >> 5)) * 64
                                   + ((jr & 15) * 4 + ((d >> 3) & 3))) * 8 + (d & 7);
                    ((ushort_t*)out0)[addr] = f2b(c);
                } else if (EPI == 4) {
                    int kk = gm >> 3, b = gm & 7;
                    int h = gn >> 6, d = gn & 63;
                    size_t addr = ((((((size_t)(b * 16 + h)) * 8 + (kk >> 7)) * 8 + ((kk >> 4) & 7)) * 2 + (d >> 5)) * 64
                                   + ((kk & 15) * 4 + ((d >> 3) & 3))) * 8 + (d & 7);
                    ((ushort_t*)out0)[addr] = f2b(c);
                } else {
                    if (f32m) ((float*)out0)[gm * 1024 + gn] = c;
                    else ((ushort_t*)out0)[gm * 1024 + gn] = f2b(c);
                }
            }
        }
    }
}

// standalone GEMM wrapper (v proj, out proj)
template<int EPI>
__global__ __launch_bounds__(256) void gemm_kernel(
    const void* Av, const ushort_t* BT, int M,
    const void* bias, const void* Up, const void* Vp,
    void* out0, void* out1, const int* flags, int a_mode) {
    __shared__ ushort_t As[4096];
    __shared__ ushort_t Bs[4096];
    gemm_body<EPI>(blockIdx.x, blockIdx.y, Av, BT, bias, Up, Vp, out0, out1, flags, a_mode, As, Bs);
}

// merged proj1: q (256 blocks) + k (512 blocks) + R (64 blocks) = 832 blocks
__global__ __launch_bounds__(256) void proj1_kernel(
    const ushort_t* qbf, const ushort_t* WqT, const void* bq, const void* Up, const void* Vp,
    ushort_t* qUw, ushort_t* qVw,
    const ushort_t* kbf, const ushort_t* WkT, const void* bk, ushort_t* khw,
    const void* pos_raw, const ushort_t* WposT, ushort_t* Rlw,
    const int* flags) {
    __shared__ ushort_t As[4096];
    __shared__ ushort_t Bs[4096];
    const int bid = blockIdx.x;
    if (bid < 256) {
        gemm_body<0>(bid & 31, bid >> 5, qbf, WqT, bq, Up, Vp, qUw, qVw, flags, 0, As, Bs);
    } else if (bid < 768) {
        int l = bid - 256;
        gemm_body<4>(l & 63, l >> 6, kbf, WkT, bk, nullptr, nullptr, khw, nullptr, flags, 0, As, Bs);
    } else {
        int l = bid - 768;
        gemm_body<2>(l & 7, l >> 3, pos_raw, WposT, nullptr, nullptr, nullptr, Rlw, nullptr, flags, 1, As, Bs);
    }
}

// ---------------- merged pre-attn: vtrans (2048 blocks) + maskprep (512 blocks) ----------------
__global__ __launch_bounds__(256) void preattn_kernel(
    const ushort_t* __restrict__ vh, ushort_t* __restrict__ vT,
    const void* __restrict__ mask, const void* __restrict__ pad,
    uint_t* __restrict__ bits, const int* flags) {
    __shared__ ushort_t t[64][68];
    const int bid = blockIdx.x;
    const int tid = threadIdx.x;
    if (bid < 2048) {
        int bh = bid >> 4;
        int k0 = (bid & 15) * 64;
        int r = tid >> 2, c0 = (tid & 3) * 16;
        const short8* src = (const short8*)&vh[((size_t)bh * 1024 + k0 + r) * 64 + c0];
        *(short8*)&t[r][c0] = src[0];
        *(short8*)&t[r][c0 + 8] = src[1];
        __syncthreads();
        ushort_t tmp[16];
        #pragma unroll
        for (int j = 0; j < 16; ++j) tmp[j] = t[c0 + j][r];
        int dm = r >> 4, cc = r & 15;
        #pragma unroll
        for (int tt = 0; tt < 2; ++tt) {
            int og = ((k0 + c0) >> 3) + tt;
            int kc = og >> 4, ch = (og >> 2) & 3, g = og & 3;
            size_t addr = ((((((size_t)bh * 8 + kc) * 4 + ch) * 4 + dm) * 64) + cc * 4 + g) * 8;
            *(short8*)&vT[addr] = *(short8*)&tmp[tt * 8];
        }
    } else {
        int tid2 = (bid - 2048) * 256 + tid;   // 131072 threads
        int w = tid2 & 31, q = (tid2 >> 5) & 511, b = tid2 >> 14;
        int mm = flags[1], f32m = flags[0];
        float padq = ldf(pad, b * 512 + q, f32m);
        uint_t word = 0;
        for (int j = 0; j < 32; ++j) {
            int k = w * 32 + j;
            size_t mi = (size_t)q * 1024 + k;
            int dead;
            if (mm == 1) dead = (((const uchar_t*)mask)[mi] != 0);
            else if (mm == 2) dead = (((const ushort_t*)mask)[mi] != 0);
            else dead = (((const uint_t*)mask)[mi] != 0);
            if (k >= 512) {
                float padk = ldf(pad, b * 512 + k - 512, f32m);
                if (padq == 0.f || padk == 0.f) dead = 1;
            }
            word |= ((uint_t)dead) << j;
        }
        bits[((b * 8 + (w >> 2)) * 512 + q) * 4 + (w & 3)] = word;
    }
}

// ---------------- fused attention (fragment-native loads, uniform wrap paths) ----------------
// block: 16 q-rows x one (b,h); 8 waves, wave w owns k in [w*128, w*128+128)
#define SP_STR 1032
#define PB_STR 136
__global__ __launch_bounds__(512, 4) void attn_kernel(
    const ushort_t* __restrict__ qU, const ushort_t* __restrict__ qV,
    const ushort_t* __restrict__ khn, const ushort_t* __restrict__ vtn,
    const ushort_t* __restrict__ Rln, const uint_t* __restrict__ mbits,
    ushort_t* __restrict__ alpha) {

    __shared__ __align__(16) uchar_t uni[35104];
    ushort_t* sPos = (ushort_t*)uni;
    ushort_t* sPb  = (ushort_t*)uni;
    float*    sO   = (float*)uni;
    __shared__ float sred[2][8][16];
    __shared__ float ssinv[16];

    const int tid = threadIdx.x;
    const int wid = tid >> 6, lane = tid & 63;
    const int g = lane >> 4, c = lane & 15;
    const int qt = blockIdx.x;
    const int q0 = qt * 16;
    const int bh = blockIdx.y;
    const int b = bh >> 4, h = bh & 15;
    const int kbase = wid * 128;
    const int lch = (c * 4 + g) * 8;

    // ---- position: PR^T[j][q] = R[j] . qV[q] -> sPos (bf16)
    {
        size_t qvb = ((size_t)bh * 32 + qt) * 1024;
        short8 bva0 = *(const short8*)&qV[qvb + lch];
        short8 bva1 = *(const short8*)&qV[qvb + 512 + lch];
        int qtb = (qt == 31) ? 31 : qt + 1;
        int cb = (qt == 31) ? 15 : c;
        size_t qvb2 = ((size_t)bh * 32 + qtb) * 1024;
        short8 bvb0 = *(const short8*)&qV[qvb2 + (cb * 4 + g) * 8];
        short8 bvb1 = *(const short8*)&qV[qvb2 + 512 + (cb * 4 + g) * 8];
        #pragma unroll
        for (int m = 0; m < 8; ++m) {
            size_t rb = ((((size_t)h * 8 + wid) * 8 + m) * 2) * 512;
            short8 ra0 = *(const short8*)&Rln[rb + lch];
            short8 ra1 = *(const short8*)&Rln[rb + 512 + lch];
            f32x4 p0 = (f32x4){0.f, 0.f, 0.f, 0.f};
            p0 = MFMA16(ra0, bva0, p0);
            p0 = MFMA16(ra1, bva1, p0);
            f32x4 p1 = (f32x4){0.f, 0.f, 0.f, 0.f};
            p1 = MFMA16(ra0, bvb0, p1);
            p1 = MFMA16(ra1, bvb1, p1);
            uint2 w;
            w.x = pk2(p0[0], p0[1]);
            w.y = pk2(p0[2], p0[3]);
            *(uint2*)&sPos[c * SP_STR + kbase + m * 16 + g * 4] = w;
            if (c == 0) {
                uint2 x;
                x.x = pk2(p1[0], p1[1]);
                x.y = pk2(p1[2], p1[3]);
                *(uint2*)&sPos[16 * SP_STR + kbase + m * 16 + g * 4] = x;
            }
        }
    }

    // ---- content: S^T[k][q] = K[k] . qU[q]
    f32x4 acc[8];
    {
        size_t qub = ((size_t)bh * 32 + qt) * 1024;
        short8 bu0 = *(const short8*)&qU[qub + lch];
        short8 bu1 = *(const short8*)&qU[qub + 512 + lch];
        #pragma unroll
        for (int m = 0; m < 8; ++m) {
            size_t kb = ((((size_t)bh * 8 + wid) * 8 + m) * 2) * 512;
            short8 ka0 = *(const short8*)&khn[kb + lch];
            short8 ka1 = *(const short8*)&khn[kb + 512 + lch];
            f32x4 t = (f32x4){0.f, 0.f, 0.f, 0.f};
            t = MFMA16(ka0, bu0, t);
            t = MFMA16(ka1, bu1, t);
            acc[m] = t;
        }
    }
    __syncthreads();

    // ---- mask bits: one coalesced uint4 per thread
    const int q = q0 + c;
    uint4 mw = *(const uint4*)(mbits + ((size_t)(b * 8 + wid) * 512 + q) * 4);
    uint_t mwa[4] = {mw.x, mw.y, mw.z, mw.w};

    // ---- score: rel-shifted position + mask; wave-uniform wrap classification
    // delta = mb + (g*4+jj) - c, mb = kbase - q0 + m*16 (uniform per wave,m)
    const int mbase = kbase - q0;
    float mx = -3.0e38f;
    #pragma unroll
    for (int m = 0; m < 8; ++m) {
        const int mb = mbase + m * 16;
        uint_t word = mwa[m >> 1];
        if (mb + 15 <= 512) {
            // all lanes non-wrap, no delta==513: j = delta+511, row c, contiguous
            int a0 = c * SP_STR + mb + g * 4 - c + 511;
            #pragma unroll
            for (int jj = 0; jj < 4; ++jj) {
                float s = acc[m][jj] + b2f(sPos[a0 + jj]);
                if ((word >> ((m & 1) * 16 + g * 4 + jj)) & 1u) s = -1e20f;
                acc[m][jj] = s;
                mx = fmaxf(mx, s);
            }
        } else if (mb - 15 >= 514) {
            // all lanes wrap, no delta==513: j = delta-514, row c+1, contiguous
            int a0 = (c + 1) * SP_STR + mb + g * 4 - c - 514;
            #pragma unroll
            for (int jj = 0; jj < 4; ++jj) {
                float s = acc[m][jj] + b2f(sPos[a0 + jj]);
                if ((word >> ((m & 1) * 16 + g * 4 + jj)) & 1u) s = -1e20f;
                acc[m][jj] = s;
                mx = fmaxf(mx, s);
            }
        } else {
            #pragma unroll
            for (int jj = 0; jj < 4; ++jj) {
                int delta = mb + g * 4 + jj - c;
                int wrap = (delta > 512) ? 1 : 0;
                int j = wrap ? (delta - 514) : (delta + 511);
                float pos = b2f(sPos[(c + wrap) * SP_STR + j]);
                if (delta == 513) pos = 0.f;
                float s = acc[m][jj] + pos;
                if ((word >> ((m & 1) * 16 + g * 4 + jj)) & 1u) s = -1e20f;
                acc[m][jj] = s;
                mx = fmaxf(mx, s);
            }
        }
    }
    mx = fmaxf(mx, __shfl_xor(mx, 16, 64));
    mx = fmaxf(mx, __shfl_xor(mx, 32, 64));
    if (lane < 16) sred[0][wid][c] = mx;
    __syncthreads();   // all sPos reads done before sPb overlay
    {
        float a0 = fmaxf(fmaxf(sred[0][0][c], sred[0][1][c]), fmaxf(sred[0][2][c], sred[0][3][c]));
        float a1 = fmaxf(fmaxf(sred[0][4][c], sred[0][5][c]), fmaxf(sred[0][6][c], sred[0][7][c]));
        mx = fmaxf(a0, a1);
    }

    // ---- exp + pack P (bf16) into sPb
    float ls = 0.f;
    #pragma unroll
    for (int m = 0; m < 8; ++m) {
        float p0 = __expf(acc[m][0] - mx);
        float p1 = __expf(acc[m][1] - mx);
        float p2 = __expf(acc[m][2] - mx);
        float p3 = __expf(acc[m][3] - mx);
        ls += (p0 + p1) + (p2 + p3);
        uint2 w;
        w.x = pk2(p0, p1);
        w.y = pk2(p2, p3);
        *(uint2*)&sPb[(wid * 16 + c) * PB_STR + m * 16 + g * 4] = w;
    }
    ls += __shfl_xor(ls, 16, 64);
    ls += __shfl_xor(ls, 32, 64);
    if (lane < 16) sred[1][wid][c] = ls;

    // ---- PV: V loads (coalesced 1KB chunks)
    short8 va[4][4];
    #pragma unroll
    for (int ch = 0; ch < 4; ++ch)
        #pragma unroll
        for (int dm = 0; dm < 4; ++dm)
            va[ch][dm] = *(const short8*)&vtn[((((((size_t)bh * 8 + wid) * 4 + ch) * 4 + dm) * 64) * 8) + lch];
    __syncthreads();
    float ls2;
    {
        float a0 = (sred[1][0][c] + sred[1][1][c]) + (sred[1][2][c] + sred[1][3][c]);
        float a1 = (sred[1][4][c] + sred[1][5][c]) + (sred[1][6][c] + sred[1][7][c]);
        ls2 = a0 + a1;
    }
    if (wid == 0 && lane < 16) ssinv[c] = 1.0f / ls2;

    f32x4 oacc[4];
    #pragma unroll
    for (int dm = 0; dm < 4; ++dm) oacc[dm] = (f32x4){0.f, 0.f, 0.f, 0.f};
    short8 pbv[4];
    #pragma unroll
    for (int ch = 0; ch < 4; ++ch)
        pbv[ch] = *(const short8*)&sPb[(wid * 16 + c) * PB_STR + ch * 32 + g * 8];
    #pragma unroll
    for (int ch = 0; ch < 4; ++ch)
        #pragma unroll
        for (int dm = 0; dm < 4; ++dm)
            oacc[dm] = MFMA16(va[ch][dm], pbv[ch], oacc[dm]);

    // cross-wave O reduction
    __syncthreads();
    #pragma unroll
    for (int dm = 0; dm < 4; ++dm)
        #pragma unroll
        for (int jj = 0; jj < 4; ++jj)
            sO[wid * 1088 + (dm * 16 + g * 4 + jj) * 17 + c] = oacc[dm][jj];
    __syncthreads();
    for (int e = tid; e < 1024; e += 512) {
        int d = e & 63, qq = e >> 6;
        float v = ((sO[d * 17 + qq] + sO[1088 + d * 17 + qq]) +
                   (sO[2176 + d * 17 + qq] + sO[3264 + d * 17 + qq])) +
                  ((sO[4352 + d * 17 + qq] + sO[5440 + d * 17 + qq]) +
                   (sO[6528 + d * 17 + qq] + sO[7616 + d * 17 + qq]));
        v *= ssinv[qq];
        alpha[((size_t)(q0 + qq) * 8 + b) * 1024 + h * 64 + d] = f2b(v);
    }
}

// ---------------- launcher ----------------
// Workspace: EXACTLY 88,081,408 bytes (proven footprint), proven alias scheme.
// Launch order: detect -> prep -> proj1(q,k,R) -> proj2(v) -> preattn(vtrans+maskprep)
//               -> attn -> outGEMM.   (12 -> 7 launches)
extern "C" void kernel_launch(void* const* d_in, const int* in_sizes, int n_in,
                              void* d_out, int out_size, void* d_ws, size_t ws_size,
                              hipStream_t stream) {
    char* ws = (char*)d_ws;
    int* flags = (int*)ws;
    ushort_t* WqT   = (ushort_t*)(ws + 1024);
    ushort_t* WkT   = WqT + 1048576;
    ushort_t* WvT   = WkT + 1048576;
    ushort_t* WposT = WvT + 1048576;
    ushort_t* WoT   = WposT + 1048576;
    ushort_t* qUw   = WoT + 1048576;            // 4,194,304
    ushort_t* qVw   = qUw + 4194304;            // 4,194,304
    ushort_t* khw   = qVw + 4194304;            // 8,388,608
    ushort_t* Rlw   = khw + 8388608;            // 1,048,576
    ushort_t* R1    = Rlw + 1048576;            // 4,194,304
    ushort_t* R2    = R1 + 4194304;             // 8,388,608
    ushort_t* R3    = R2 + 8388608;             // 8,388,608
    // aliases (lifetime-disjoint, stream-ordered):
    ushort_t* qbf = R1;     // prep out -> read by proj1 -> dead
    ushort_t* alw = R1;     // attn out -> read by outGEMM
    ushort_t* kbf = R2;     // prep out -> read by proj1 -> dead
    ushort_t* vhw = R2;     // proj2 out -> read by preattn -> dead
    ushort_t* vbf = R3;     // prep out -> read by proj2 -> dead
    ushort_t* vTw = R3;     // preattn out -> read by attn
    uint_t* mbits = (uint_t*)WqT;  // preattn out (WqT dead after proj1)

    detect_kernel<<<1, 256, 0, stream>>>(d_in[6], d_in[7], flags);
    // merged converts (q,k,v) + 5 weight transposes
    prep_kernel<<<15360, 256, 0, stream>>>(
        d_in[0], qbf, d_in[1], kbf, d_in[2], vbf,
        d_in[8], d_in[10], d_in[12], d_in[14], d_in[15],
        WqT, WkT, WvT, WposT, WoT, flags);
    // merged q + k + R projections (832 blocks, ~3.25/CU co-residency)
    proj1_kernel<<<832, 256, 0, stream>>>(
        qbf, WqT, d_in[9], d_in[4], d_in[5], qUw, qVw,
        kbf, WkT, d_in[11], khw,
        d_in[3], WposT, Rlw, flags);
    // v projection (writes into dead kbf region)
    gemm_kernel<1><<<dim3(64, 8), 256, 0, stream>>>(vbf, WvT, 8192, d_in[13], nullptr, nullptr, vhw, nullptr, flags, 0);
    // merged vtrans + maskprep
    preattn_kernel<<<2560, 256, 0, stream>>>(vhw, vTw, d_in[6], d_in[7], mbits, flags);
    // fused attention
    attn_kernel<<<dim3(32, 128), 512, 0, stream>>>(qUw, qVw, khw, vTw, Rlw, mbits, alw);
    // output projection
    gemm_kernel<3><<<dim3(32, 8), 256, 0, stream>>>(alw, WoT, 4096, d_in[16], nullptr, nullptr, d_out, nullptr, flags, 0);
}